// Round 4
// baseline (660.801 us; speedup 1.0000x reference)
//
#include <hip/hip_runtime.h>

#define LQ 2048
#define LK 2048
#define BB 16
#define DD 512
#define DKK 64
#define EPSF 1e-9f

typedef unsigned short u16;
typedef __attribute__((ext_vector_type(8))) short bf16x8;
typedef __attribute__((ext_vector_type(4))) float f32x4;
#define MFMA16(a, b, c) __builtin_amdgcn_mfma_f32_16x16x32_bf16(a, b, c, 0, 0, 0)

__device__ inline u16 f2bf(float f) {
    unsigned int u = __float_as_uint(f);
    u += 0x7fffu + ((u >> 16) & 1u);   // RNE
    return (u16)(u >> 16);
}
__device__ inline bf16x8 cvt8(float4 a, float4 b) {
    bf16x8 r;
    r[0] = (short)f2bf(a.x); r[1] = (short)f2bf(a.y); r[2] = (short)f2bf(a.z); r[3] = (short)f2bf(a.w);
    r[4] = (short)f2bf(b.x); r[5] = (short)f2bf(b.y); r[6] = (short)f2bf(b.z); r[7] = (short)f2bf(b.w);
    return r;
}

__global__ __launch_bounds__(256) void k_cvt(const float* __restrict__ src, u16* __restrict__ dst, int n) {
    int i = (blockIdx.x * 256 + threadIdx.x) * 4;
    if (i < n) {
        float4 v = *reinterpret_cast<const float4*>(src + i);
        *reinterpret_cast<ushort4*>(dst + i) = make_ushort4(f2bf(v.x), f2bf(v.y), f2bf(v.z), f2bf(v.w));
    }
}

// y[b][l][dk] = l2norm( x[l,b,:] @ Wb[dk,:] )
__global__ __launch_bounds__(256) void k_projqk(const float* __restrict__ x, const u16* __restrict__ Wb,
                                                u16* __restrict__ y)
{
    const int b = blockIdx.y, r0 = blockIdx.x * 128;
    const int tid = threadIdx.x, wave = tid >> 6, lane = tid & 63, l15 = lane & 15, g = lane >> 4;
    const int rw = r0 + wave * 32;
    f32x4 z = {0.f, 0.f, 0.f, 0.f};
    f32x4 acc[2][4];
#pragma unroll
    for (int m = 0; m < 2; m++)
#pragma unroll
        for (int nf = 0; nf < 4; nf++) acc[m][nf] = z;

    for (int kt = 0; kt < DD; kt += 32) {
        bf16x8 af[2];
#pragma unroll
        for (int m = 0; m < 2; m++) {
            const float* p = x + ((size_t)(rw + 16 * m + l15) * BB + b) * DD + kt + g * 8;
            af[m] = cvt8(*reinterpret_cast<const float4*>(p), *reinterpret_cast<const float4*>(p + 4));
        }
#pragma unroll
        for (int nf = 0; nf < 4; nf++) {
            bf16x8 bf_ = *reinterpret_cast<const bf16x8*>(Wb + (size_t)(nf * 16 + l15) * DD + kt + g * 8);
            acc[0][nf] = MFMA16(af[0], bf_, acc[0][nf]);
            acc[1][nf] = MFMA16(af[1], bf_, acc[1][nf]);
        }
    }
#pragma unroll
    for (int m = 0; m < 2; m++) {
        float rn[4];
#pragma unroll
        for (int j = 0; j < 4; j++) {
            float t2 = acc[m][0][j] * acc[m][0][j] + acc[m][1][j] * acc[m][1][j]
                     + acc[m][2][j] * acc[m][2][j] + acc[m][3][j] * acc[m][3][j];
            t2 += __shfl_xor(t2, 1, 64);
            t2 += __shfl_xor(t2, 2, 64);
            t2 += __shfl_xor(t2, 4, 64);
            t2 += __shfl_xor(t2, 8, 64);
            rn[j] = 1.f / fmaxf(sqrtf(t2), 1e-12f);
        }
#pragma unroll
        for (int nf = 0; nf < 4; nf++)
#pragma unroll
            for (int j = 0; j < 4; j++) {
                int q = rw + 16 * m + g * 4 + j;
                y[((size_t)b * LQ + q) * DKK + nf * 16 + l15] = f2bf(acc[m][nf][j] * rn[j]);
            }
    }
}

// wvT[b][d][k] = value[k,b,:] @ WVb[d,:]   BM=128 k-rows, BN=128 d, 4 waves, LDS A dbuf
__global__ __launch_bounds__(256, 3) void k_projv(const float* __restrict__ value, const u16* __restrict__ WVb,
                                                  u16* __restrict__ wvT)
{
    const int b = blockIdx.z, k0 = blockIdx.x * 128, n0 = blockIdx.y * 128;
    const int tid = threadIdx.x, lane = tid & 63, l15 = lane & 15, g = lane >> 4;
    const int wave = tid >> 6, qg = wave >> 1, dg = wave & 1;
    __shared__ __align__(16) u16 A[2][128][40];
    f32x4 z = {0.f, 0.f, 0.f, 0.f};
    f32x4 acc[4][4];
#pragma unroll
    for (int m = 0; m < 4; m++)
#pragma unroll
        for (int nf = 0; nf < 4; nf++) acc[m][nf] = z;

    const int sr = tid >> 1, sc = (tid & 1) * 16;
    auto stage = [&](int bufw, int kt) {
        const float* p = value + ((size_t)(k0 + sr) * BB + b) * DD + kt + sc;
        *reinterpret_cast<bf16x8*>(&A[bufw][sr][sc]) =
            cvt8(*reinterpret_cast<const float4*>(p), *reinterpret_cast<const float4*>(p + 4));
        *reinterpret_cast<bf16x8*>(&A[bufw][sr][sc + 8]) =
            cvt8(*reinterpret_cast<const float4*>(p + 8), *reinterpret_cast<const float4*>(p + 12));
    };
    stage(0, 0);
    __syncthreads();
    int buf = 0;
    for (int kt = 0; kt < DD; kt += 32) {
        if (kt + 32 < DD) stage(buf ^ 1, kt + 32);
        bf16x8 af[4];
#pragma unroll
        for (int m = 0; m < 4; m++)
            af[m] = *reinterpret_cast<const bf16x8*>(&A[buf][qg * 64 + m * 16 + l15][g * 8]);
#pragma unroll
        for (int nf = 0; nf < 4; nf++) {
            bf16x8 bw = *reinterpret_cast<const bf16x8*>(WVb + (size_t)(n0 + dg * 64 + nf * 16 + l15) * DD + kt + g * 8);
#pragma unroll
            for (int m = 0; m < 4; m++) acc[m][nf] = MFMA16(af[m], bw, acc[m][nf]);
        }
        __syncthreads();
        buf ^= 1;
    }
#pragma unroll
    for (int m = 0; m < 4; m++)
#pragma unroll
        for (int nf = 0; nf < 4; nf++) {
            int d = n0 + dg * 64 + nf * 16 + l15;
            size_t base = ((size_t)b * DD + d) * LK + k0 + qg * 64 + m * 16 + g * 4;
            *reinterpret_cast<ushort4*>(wvT + base) =
                make_ushort4(f2bf(acc[m][nf][0]), f2bf(acc[m][nf][1]), f2bf(acc[m][nf][2]), f2bf(acc[m][nf][3]));
        }
}

// outv[row] = 1/(eps + sum_cols exp(s)*w[col])
__global__ __launch_bounds__(256) void k_expsum(const u16* __restrict__ A, const u16* __restrict__ Bm,
                                                const float* __restrict__ wcol, float* __restrict__ outv,
                                                float eps)
{
    const int b = blockIdx.y, r0 = blockIdx.x * 64;
    const int tid = threadIdx.x, wave = tid >> 6, lane = tid & 63, l15 = lane & 15, g = lane >> 4;
    f32x4 z = {0.f, 0.f, 0.f, 0.f};

    const u16* arow = A + ((size_t)b * LK + r0 + wave * 16 + l15) * DKK;
    bf16x8 af0 = *reinterpret_cast<const bf16x8*>(arow + g * 8);
    bf16x8 af1 = *reinterpret_cast<const bf16x8*>(arow + 32 + g * 8);
    float acc[4] = {0.f, 0.f, 0.f, 0.f};

    for (int ct = 0; ct < LK; ct += 64) {
#pragma unroll
        for (int n = 0; n < 4; n++) {
            int col = ct + n * 16;
            const u16* brow = Bm + ((size_t)b * LK + col + l15) * DKK;
            bf16x8 b0 = *reinterpret_cast<const bf16x8*>(brow + g * 8);
            bf16x8 b1 = *reinterpret_cast<const bf16x8*>(brow + 32 + g * 8);
            float w = wcol ? wcol[(size_t)b * LK + col + l15] : 1.f;
            f32x4 s = z;
            s = MFMA16(af0, b0, s);
            s = MFMA16(af1, b1, s);
#pragma unroll
            for (int j = 0; j < 4; j++) acc[j] += __expf(s[j]) * w;
        }
    }
#pragma unroll
    for (int j = 0; j < 4; j++) {
        float v = acc[j];
        v += __shfl_xor(v, 1, 64);
        v += __shfl_xor(v, 2, 64);
        v += __shfl_xor(v, 4, 64);
        v += __shfl_xor(v, 8, 64);
        if (l15 == 0) outv[(size_t)b * LK + r0 + wave * 16 + g * 4 + j] = 1.f / (eps + v);
    }
}

// t[q,b,:] = query - sum_k exp(s)*Rq*ci * wv[k,:]
// 4 waves, BM=128 q, BN=128 d, BK=64; P XOR-swizzled LDS dbuf; civ prefetch
__global__ __launch_bounds__(256, 3) void k_pv(const float* __restrict__ query, const u16* __restrict__ wqb,
                                               const u16* __restrict__ wkb, const u16* __restrict__ wvT,
                                               const float* __restrict__ Rq, const float* __restrict__ ci,
                                               u16* __restrict__ tout)
{
    // XCD-pinned swizzle: XCD = i%8 hosts b in {i%8, i%8+8}
    const int i = blockIdx.x;
    const int b = (i & 7) + 8 * ((i >> 3) & 1);
    const int rest = i >> 4;                  // 0..63
    const int q0 = (rest & 15) * 128, n0 = (rest >> 4) * 128;
    const int tid = threadIdx.x, wave = tid >> 6, lane = tid & 63, l15 = lane & 15, g = lane >> 4;
    const int qg = wave >> 1, dg = wave & 1;
    __shared__ __align__(16) u16 P[2][128][64];
    f32x4 z = {0.f, 0.f, 0.f, 0.f};

    // fill-phase A-frags (wave owns P rows wave*32 .. +31)
    bf16x8 af[2][2];
    float Rr[2][4];
#pragma unroll
    for (int mm = 0; mm < 2; mm++) {
        const u16* qrow = wqb + ((size_t)b * LQ + q0 + wave * 32 + mm * 16 + l15) * DKK;
        af[mm][0] = *reinterpret_cast<const bf16x8*>(qrow + g * 8);
        af[mm][1] = *reinterpret_cast<const bf16x8*>(qrow + 32 + g * 8);
#pragma unroll
        for (int j = 0; j < 4; j++)
            Rr[mm][j] = Rq[(size_t)b * LQ + q0 + wave * 32 + mm * 16 + g * 4 + j];
    }

    f32x4 acc[4][4];
#pragma unroll
    for (int m = 0; m < 4; m++)
#pragma unroll
        for (int nf = 0; nf < 4; nf++) acc[m][nf] = z;

    float civ[4];
#pragma unroll
    for (int n = 0; n < 4; n++) civ[n] = ci[(size_t)b * LK + n * 16 + l15];

    char* Pc0 = (char*)&P[0][0][0];
    char* Pc1 = (char*)&P[1][0][0];

    auto fill = [&](char* Pb, int kt) {
#pragma unroll
        for (int n = 0; n < 4; n++) {
            const u16* krow = wkb + ((size_t)b * LK + kt + n * 16 + l15) * DKK;
            bf16x8 kf0 = *reinterpret_cast<const bf16x8*>(krow + g * 8);
            bf16x8 kf1 = *reinterpret_cast<const bf16x8*>(krow + 32 + g * 8);
#pragma unroll
            for (int mm = 0; mm < 2; mm++) {
                f32x4 s = z;
                s = MFMA16(af[mm][0], kf0, s);
                s = MFMA16(af[mm][1], kf1, s);
#pragma unroll
                for (int j = 0; j < 4; j++) {
                    int r = wave * 32 + mm * 16 + g * 4 + j;
                    int byteoff = r * 128 + ((2 * (n * 16 + l15)) ^ ((r & 7) << 4));
                    *reinterpret_cast<u16*>(Pb + byteoff) = f2bf(__expf(s[j]) * Rr[mm][j] * civ[n]);
                }
            }
        }
    };

    fill(Pc0, 0);
    __syncthreads();
    int buf = 0;
    for (int kt = 0; kt < LK; kt += 64) {
        char* Pcur = buf ? Pc1 : Pc0;
        char* Pnxt = buf ? Pc0 : Pc1;
        bf16x8 pa[4][2];
#pragma unroll
        for (int m = 0; m < 4; m++) {
            int row = qg * 64 + m * 16 + l15;
#pragma unroll
            for (int kk = 0; kk < 2; kk++)
                pa[m][kk] = *reinterpret_cast<const bf16x8*>(
                    Pcur + row * 128 + ((kk * 64 + g * 16) ^ ((row & 7) << 4)));
        }
        float civn[4];
        if (kt + 64 < LK) {
#pragma unroll
            for (int n = 0; n < 4; n++) civn[n] = ci[(size_t)b * LK + kt + 64 + n * 16 + l15];
        }
#pragma unroll
        for (int nf = 0; nf < 4; nf++) {
            const u16* vrow = wvT + ((size_t)b * DD + n0 + dg * 64 + nf * 16 + l15) * LK + kt;
            bf16x8 bv0 = *reinterpret_cast<const bf16x8*>(vrow + g * 8);
            bf16x8 bv1 = *reinterpret_cast<const bf16x8*>(vrow + 32 + g * 8);
#pragma unroll
            for (int m = 0; m < 4; m++) {
                acc[m][nf] = MFMA16(pa[m][0], bv0, acc[m][nf]);
                acc[m][nf] = MFMA16(pa[m][1], bv1, acc[m][nf]);
            }
        }
        if (kt + 64 < LK) {
#pragma unroll
            for (int n = 0; n < 4; n++) civ[n] = civn[n];
            fill(Pnxt, kt + 64);
        }
        __syncthreads();
        buf ^= 1;
    }
#pragma unroll
    for (int m = 0; m < 4; m++)
#pragma unroll
        for (int nf = 0; nf < 4; nf++)
#pragma unroll
            for (int j = 0; j < 4; j++) {
                int q = q0 + qg * 64 + m * 16 + g * 4 + j;
                int d = n0 + dg * 64 + nf * 16 + l15;
                size_t idx = ((size_t)q * BB + b) * DD + d;
                tout[idx] = f2bf(query[idx] - acc[m][nf][j]);
            }
}

// out[r][n] = relu( t[r,:] @ Wtb[n,:] )   BM=128, BN=128, 4 waves
__global__ __launch_bounds__(256, 3) void k_final(const u16* __restrict__ t, const u16* __restrict__ Wtb,
                                                  float* __restrict__ out)
{
    const int r0 = blockIdx.x * 128, n0 = blockIdx.y * 128;
    const int tid = threadIdx.x, wave = tid >> 6, lane = tid & 63, l15 = lane & 15, g = lane >> 4;
    const int qg = wave >> 1, dg = wave & 1;
    f32x4 z = {0.f, 0.f, 0.f, 0.f};
    f32x4 acc[4][4];
#pragma unroll
    for (int m = 0; m < 4; m++)
#pragma unroll
        for (int nf = 0; nf < 4; nf++) acc[m][nf] = z;

#pragma unroll 2
    for (int kt = 0; kt < DD; kt += 32) {
        bf16x8 af[4];
#pragma unroll
        for (int m = 0; m < 4; m++)
            af[m] = *reinterpret_cast<const bf16x8*>(t + (size_t)(r0 + qg * 64 + m * 16 + l15) * DD + kt + g * 8);
#pragma unroll
        for (int nf = 0; nf < 4; nf++) {
            bf16x8 bw = *reinterpret_cast<const bf16x8*>(Wtb + (size_t)(n0 + dg * 64 + nf * 16 + l15) * DD + kt + g * 8);
#pragma unroll
            for (int m = 0; m < 4; m++) acc[m][nf] = MFMA16(af[m], bw, acc[m][nf]);
        }
    }
#pragma unroll
    for (int m = 0; m < 4; m++)
#pragma unroll
        for (int nf = 0; nf < 4; nf++)
#pragma unroll
            for (int j = 0; j < 4; j++)
                out[(size_t)(r0 + qg * 64 + m * 16 + g * 4 + j) * DD + n0 + dg * 64 + nf * 16 + l15] =
                    fmaxf(acc[m][nf][j], 0.f);
}

extern "C" void kernel_launch(void* const* d_in, const int* in_sizes, int n_in,
                              void* d_out, int out_size, void* d_ws, size_t ws_size,
                              hipStream_t stream)
{
    const float* query = (const float*)d_in[0];
    const float* key   = (const float*)d_in[1];
    const float* value = (const float*)d_in[2];
    const float* WK    = (const float*)d_in[3];
    const float* WQ    = (const float*)d_in[4];
    const float* WV    = (const float*)d_in[5];
    const float* Wt    = (const float*)d_in[6];
    float* out = (float*)d_out;

    char* ws = (char*)d_ws;
    u16*   wqb = (u16*)(ws);                                   //  4 MB [B][LQ][64] bf16
    u16*   wkb = (u16*)(ws + (4u << 20));                      //  4 MB [B][LK][64] bf16
    u16*   wvT = (u16*)(ws + (8u << 20));                      // 32 MB [B][512][LK] bf16
    u16*   t   = (u16*)(ws + (40u << 20));                     // 32 MB [LQ][B][512] bf16
    float* Rq  = (float*)(ws + (72u << 20));                   // 128 KB [B][LQ] f32
    float* ci  = (float*)(ws + (72u << 20) + (128u << 10));    // 128 KB [B][LK] f32
    u16*   WQb = (u16*)(ws + (72u << 20) + (256u << 10));      // 64 KB
    u16*   WKb = (u16*)(ws + (72u << 20) + (320u << 10));      // 64 KB
    u16*   WVb = (u16*)(ws + (72u << 20) + (384u << 10));      // 512 KB
    u16*   Wtb = (u16*)(ws + (72u << 20) + (896u << 10));      // 512 KB

    k_cvt<<<32, 256, 0, stream>>>(WQ, WQb, DKK * DD);
    k_cvt<<<32, 256, 0, stream>>>(WK, WKb, DKK * DD);
    k_cvt<<<256, 256, 0, stream>>>(WV, WVb, DD * DD);
    k_cvt<<<256, 256, 0, stream>>>(Wt, Wtb, DD * DD);

    k_projqk<<<dim3(LQ / 128, BB), 256, 0, stream>>>(query, WQb, wqb);
    k_projqk<<<dim3(LK / 128, BB), 256, 0, stream>>>(key, WKb, wkb);
    k_projv <<<dim3(LK / 128, DD / 128, BB), 256, 0, stream>>>(value, WVb, wvT);

    k_expsum<<<dim3(LQ / 64, BB), 256, 0, stream>>>(wqb, wkb, nullptr, Rq, 0.f);
    k_expsum<<<dim3(LK / 64, BB), 256, 0, stream>>>(wkb, wqb, Rq, ci, EPSF);

    k_pv<<<1024, 256, 0, stream>>>(query, wqb, wkb, wvT, Rq, ci, t);
    k_final<<<dim3(256, 4), 256, 0, stream>>>(t, Wtb, out);
}

// Round 5
// 577.370 us; speedup vs baseline: 1.1445x; 1.1445x over previous
//
#include <hip/hip_runtime.h>

#define LQ 2048
#define LK 2048
#define BB 16
#define DD 512
#define DKK 64
#define EPSF 1e-9f

typedef unsigned short u16;
typedef __attribute__((ext_vector_type(8))) short bf16x8;
typedef __attribute__((ext_vector_type(4))) float f32x4;
#define MFMA16(a, b, c) __builtin_amdgcn_mfma_f32_16x16x32_bf16(a, b, c, 0, 0, 0)

__device__ inline u16 f2bf(float f) {
    unsigned int u = __float_as_uint(f);
    u += 0x7fffu + ((u >> 16) & 1u);   // RNE
    return (u16)(u >> 16);
}
__device__ inline bf16x8 cvt8(float4 a, float4 b) {
    bf16x8 r;
    r[0] = (short)f2bf(a.x); r[1] = (short)f2bf(a.y); r[2] = (short)f2bf(a.z); r[3] = (short)f2bf(a.w);
    r[4] = (short)f2bf(b.x); r[5] = (short)f2bf(b.y); r[6] = (short)f2bf(b.z); r[7] = (short)f2bf(b.w);
    return r;
}

__global__ __launch_bounds__(256) void k_cvt(const float* __restrict__ src, u16* __restrict__ dst, int n) {
    int i = (blockIdx.x * 256 + threadIdx.x) * 4;
    if (i < n) {
        float4 v = *reinterpret_cast<const float4*>(src + i);
        *reinterpret_cast<ushort4*>(dst + i) = make_ushort4(f2bf(v.x), f2bf(v.y), f2bf(v.z), f2bf(v.w));
    }
}

// y[b][l][dk] = l2norm( x[l,b,:] @ Wb[dk,:] )
__global__ __launch_bounds__(256) void k_projqk(const float* __restrict__ x, const u16* __restrict__ Wb,
                                                u16* __restrict__ y)
{
    const int b = blockIdx.y, r0 = blockIdx.x * 128;
    const int tid = threadIdx.x, wave = tid >> 6, lane = tid & 63, l15 = lane & 15, g = lane >> 4;
    const int rw = r0 + wave * 32;
    f32x4 z = {0.f, 0.f, 0.f, 0.f};
    f32x4 acc[2][4];
#pragma unroll
    for (int m = 0; m < 2; m++)
#pragma unroll
        for (int nf = 0; nf < 4; nf++) acc[m][nf] = z;

    for (int kt = 0; kt < DD; kt += 32) {
        bf16x8 af[2];
#pragma unroll
        for (int m = 0; m < 2; m++) {
            const float* p = x + ((size_t)(rw + 16 * m + l15) * BB + b) * DD + kt + g * 8;
            af[m] = cvt8(*reinterpret_cast<const float4*>(p), *reinterpret_cast<const float4*>(p + 4));
        }
#pragma unroll
        for (int nf = 0; nf < 4; nf++) {
            bf16x8 bf_ = *reinterpret_cast<const bf16x8*>(Wb + (size_t)(nf * 16 + l15) * DD + kt + g * 8);
            acc[0][nf] = MFMA16(af[0], bf_, acc[0][nf]);
            acc[1][nf] = MFMA16(af[1], bf_, acc[1][nf]);
        }
    }
#pragma unroll
    for (int m = 0; m < 2; m++) {
        float rn[4];
#pragma unroll
        for (int j = 0; j < 4; j++) {
            float t2 = acc[m][0][j] * acc[m][0][j] + acc[m][1][j] * acc[m][1][j]
                     + acc[m][2][j] * acc[m][2][j] + acc[m][3][j] * acc[m][3][j];
            t2 += __shfl_xor(t2, 1, 64);
            t2 += __shfl_xor(t2, 2, 64);
            t2 += __shfl_xor(t2, 4, 64);
            t2 += __shfl_xor(t2, 8, 64);
            rn[j] = 1.f / fmaxf(sqrtf(t2), 1e-12f);
        }
#pragma unroll
        for (int nf = 0; nf < 4; nf++)
#pragma unroll
            for (int j = 0; j < 4; j++) {
                int q = rw + 16 * m + g * 4 + j;
                y[((size_t)b * LQ + q) * DKK + nf * 16 + l15] = f2bf(acc[m][nf][j] * rn[j]);
            }
    }
}

// wvS[b][d][k] = (value[k,b,:] @ WVb[d,:]) * (ci ? ci[b][k] : 1)
__global__ __launch_bounds__(256) void k_projv(const float* __restrict__ value, const u16* __restrict__ WVb,
                                               const float* __restrict__ ci, u16* __restrict__ wvS, int b0)
{
    const int b = b0 + blockIdx.z, k0 = blockIdx.x * 128, n0 = blockIdx.y * 128;
    const int tid = threadIdx.x, lane = tid & 63, l15 = lane & 15, g = lane >> 4;
    const int wave = tid >> 6, qg = wave >> 1, dg = wave & 1;
    __shared__ __align__(16) u16 A[2][128][40];
    f32x4 z = {0.f, 0.f, 0.f, 0.f};
    f32x4 acc[4][4];
#pragma unroll
    for (int m = 0; m < 4; m++)
#pragma unroll
        for (int nf = 0; nf < 4; nf++) acc[m][nf] = z;

    const int sr = tid >> 1, sc = (tid & 1) * 16;
    auto stage = [&](int bufw, int kt) {
        const float* p = value + ((size_t)(k0 + sr) * BB + b) * DD + kt + sc;
        *reinterpret_cast<bf16x8*>(&A[bufw][sr][sc]) =
            cvt8(*reinterpret_cast<const float4*>(p), *reinterpret_cast<const float4*>(p + 4));
        *reinterpret_cast<bf16x8*>(&A[bufw][sr][sc + 8]) =
            cvt8(*reinterpret_cast<const float4*>(p + 8), *reinterpret_cast<const float4*>(p + 12));
    };
    stage(0, 0);
    __syncthreads();
    int buf = 0;
    for (int kt = 0; kt < DD; kt += 32) {
        if (kt + 32 < DD) stage(buf ^ 1, kt + 32);
        bf16x8 af[4];
#pragma unroll
        for (int m = 0; m < 4; m++)
            af[m] = *reinterpret_cast<const bf16x8*>(&A[buf][qg * 64 + m * 16 + l15][g * 8]);
#pragma unroll
        for (int nf = 0; nf < 4; nf++) {
            bf16x8 bw = *reinterpret_cast<const bf16x8*>(WVb + (size_t)(n0 + dg * 64 + nf * 16 + l15) * DD + kt + g * 8);
#pragma unroll
            for (int m = 0; m < 4; m++) acc[m][nf] = MFMA16(af[m], bw, acc[m][nf]);
        }
        __syncthreads();
        buf ^= 1;
    }
#pragma unroll
    for (int m = 0; m < 4; m++) {
        float cv[4] = {1.f, 1.f, 1.f, 1.f};
        if (ci) {
#pragma unroll
            for (int j = 0; j < 4; j++)
                cv[j] = ci[(size_t)b * LK + k0 + qg * 64 + m * 16 + g * 4 + j];
        }
#pragma unroll
        for (int nf = 0; nf < 4; nf++) {
            int d = n0 + dg * 64 + nf * 16 + l15;
            size_t base = ((size_t)b * DD + d) * LK + k0 + qg * 64 + m * 16 + g * 4;
            *reinterpret_cast<ushort4*>(wvS + base) =
                make_ushort4(f2bf(acc[m][nf][0] * cv[0]), f2bf(acc[m][nf][1] * cv[1]),
                             f2bf(acc[m][nf][2] * cv[2]), f2bf(acc[m][nf][3] * cv[3]));
        }
    }
}

// outv[row] = 1/(eps + sum_cols exp(s)*w[col]);  optionally E[col][row] = bf16(exp(s)*w[col])
// A rows = out rows; B rows = cols. E is group-local: chunk index = blockIdx.y.
__global__ __launch_bounds__(256) void k_expsum(const u16* __restrict__ A, const u16* __restrict__ Bm,
                                                const float* __restrict__ wcol, float* __restrict__ outv,
                                                float eps, u16* __restrict__ E, int b0)
{
    const int b = b0 + blockIdx.y, r0 = blockIdx.x * 64;
    const int tid = threadIdx.x, wave = tid >> 6, lane = tid & 63, l15 = lane & 15, g = lane >> 4;
    f32x4 z = {0.f, 0.f, 0.f, 0.f};
    u16* Eb = E ? (E + (size_t)blockIdx.y * LQ * LK) : nullptr;

    const u16* arow = A + ((size_t)b * LK + r0 + wave * 16 + l15) * DKK;
    bf16x8 af0 = *reinterpret_cast<const bf16x8*>(arow + g * 8);
    bf16x8 af1 = *reinterpret_cast<const bf16x8*>(arow + 32 + g * 8);
    float acc[4] = {0.f, 0.f, 0.f, 0.f};

    for (int ct = 0; ct < LK; ct += 64) {
#pragma unroll
        for (int n = 0; n < 4; n++) {
            int col = ct + n * 16;
            const u16* brow = Bm + ((size_t)b * LK + col + l15) * DKK;
            bf16x8 b0v = *reinterpret_cast<const bf16x8*>(brow + g * 8);
            bf16x8 b1v = *reinterpret_cast<const bf16x8*>(brow + 32 + g * 8);
            float w = wcol ? wcol[(size_t)b * LK + col + l15] : 1.f;
            f32x4 s = z;
            s = MFMA16(af0, b0v, s);
            s = MFMA16(af1, b1v, s);
            float pe[4];
#pragma unroll
            for (int j = 0; j < 4; j++) {
                pe[j] = __expf(s[j]) * w;
                acc[j] += pe[j];
            }
            if (Eb) {
                // lane's values: row k = r0+wave*16+g*4+j (A rows), col q = col+l15 (B rows)
                // E[q][k]: k is fast axis -> ushort4 contiguous
                size_t idx = (size_t)(col + l15) * LK + r0 + wave * 16 + g * 4;
                *reinterpret_cast<ushort4*>(Eb + idx) =
                    make_ushort4(f2bf(pe[0]), f2bf(pe[1]), f2bf(pe[2]), f2bf(pe[3]));
            }
        }
    }
#pragma unroll
    for (int j = 0; j < 4; j++) {
        float v = acc[j];
        v += __shfl_xor(v, 1, 64);
        v += __shfl_xor(v, 2, 64);
        v += __shfl_xor(v, 4, 64);
        v += __shfl_xor(v, 8, 64);
        if (l15 == 0) outv[(size_t)b * LK + r0 + wave * 16 + g * 4 + j] = 1.f / (eps + v);
    }
}

// t[q,b,:] = query[q,b,:] - E[q,:] @ wvS[b][:, :]^T    pure GEMM, no LDS, no barriers
// E group-local [G][LQ][LK] bf16; wvS [B][DD][LK] bf16
__global__ __launch_bounds__(256) void k_pvgemm(const float* __restrict__ query, const u16* __restrict__ E,
                                                const u16* __restrict__ wvS, u16* __restrict__ tout,
                                                int b0, int G)
{
    const int i = blockIdx.x;
    const int bl = i % G, tile = i / G;     // consecutive blocks cycle b -> XCD-pinned for G>=8
    const int b = b0 + bl;
    const int n0 = (tile & 3) * 128, q0 = (tile >> 2) * 128;
    const int tid = threadIdx.x, wave = tid >> 6, lane = tid & 63, l15 = lane & 15, g = lane >> 4;
    const int qg = wave >> 1, dg = wave & 1;
    f32x4 z = {0.f, 0.f, 0.f, 0.f};

    const u16* Eb = E + (size_t)bl * LQ * LK;
    const u16* Vb = wvS + (size_t)b * DD * LK;

    f32x4 acc[4][4];
#pragma unroll
    for (int m = 0; m < 4; m++)
#pragma unroll
        for (int nf = 0; nf < 4; nf++) acc[m][nf] = z;

    for (int kt = 0; kt < LK; kt += 64) {
        bf16x8 af[4][2], bv[4][2];
#pragma unroll
        for (int m = 0; m < 4; m++) {
            const u16* erow = Eb + (size_t)(q0 + qg * 64 + m * 16 + l15) * LK + kt;
            af[m][0] = *reinterpret_cast<const bf16x8*>(erow + g * 8);
            af[m][1] = *reinterpret_cast<const bf16x8*>(erow + 32 + g * 8);
        }
#pragma unroll
        for (int nf = 0; nf < 4; nf++) {
            const u16* vrow = Vb + (size_t)(n0 + dg * 64 + nf * 16 + l15) * LK + kt;
            bv[nf][0] = *reinterpret_cast<const bf16x8*>(vrow + g * 8);
            bv[nf][1] = *reinterpret_cast<const bf16x8*>(vrow + 32 + g * 8);
        }
#pragma unroll
        for (int nf = 0; nf < 4; nf++)
#pragma unroll
            for (int m = 0; m < 4; m++) {
                acc[m][nf] = MFMA16(af[m][0], bv[nf][0], acc[m][nf]);
                acc[m][nf] = MFMA16(af[m][1], bv[nf][1], acc[m][nf]);
            }
    }
#pragma unroll
    for (int m = 0; m < 4; m++)
#pragma unroll
        for (int nf = 0; nf < 4; nf++)
#pragma unroll
            for (int j = 0; j < 4; j++) {
                int q = q0 + qg * 64 + m * 16 + g * 4 + j;
                int d = n0 + dg * 64 + nf * 16 + l15;
                size_t idx = ((size_t)q * BB + b) * DD + d;
                tout[idx] = f2bf(query[idx] - acc[m][nf][j]);
            }
}

// fallback (R3-proven): inline-recompute PV, BM=128 q, BN=256 d, 8 waves
__global__ __launch_bounds__(512) void k_pv_fb(const float* __restrict__ query, const u16* __restrict__ wqb,
                                               const u16* __restrict__ wkb, const u16* __restrict__ wvT,
                                               const float* __restrict__ Rq, const float* __restrict__ ci,
                                               u16* __restrict__ tout)
{
    const int i = blockIdx.x;
    const int b = (i & 7) + 8 * ((i >> 3) & 1);
    const int rest = i >> 4;
    const int q0 = (rest & 15) * 128, n0 = (rest >> 4) * 256;
    const int tid = threadIdx.x, wave = tid >> 6, lane = tid & 63, l15 = lane & 15, g = lane >> 4;
    const int qg = wave >> 2, dg = wave & 3;
    __shared__ __align__(16) u16 P[2][128][72];
    f32x4 z = {0.f, 0.f, 0.f, 0.f};

    const u16* qrow = wqb + ((size_t)b * LQ + q0 + wave * 16 + l15) * DKK;
    bf16x8 qf0 = *reinterpret_cast<const bf16x8*>(qrow + g * 8);
    bf16x8 qf1 = *reinterpret_cast<const bf16x8*>(qrow + 32 + g * 8);
    float Rr[4];
#pragma unroll
    for (int j = 0; j < 4; j++) Rr[j] = Rq[(size_t)b * LQ + q0 + wave * 16 + g * 4 + j];

    f32x4 acc[4][4];
#pragma unroll
    for (int m = 0; m < 4; m++)
#pragma unroll
        for (int nf = 0; nf < 4; nf++) acc[m][nf] = z;

    auto fill = [&](int bufw, int kt) {
#pragma unroll
        for (int n = 0; n < 4; n++) {
            const u16* krow = wkb + ((size_t)b * LK + kt + n * 16 + l15) * DKK;
            bf16x8 kf0 = *reinterpret_cast<const bf16x8*>(krow + g * 8);
            bf16x8 kf1 = *reinterpret_cast<const bf16x8*>(krow + 32 + g * 8);
            float civ = ci[(size_t)b * LK + kt + n * 16 + l15];
            f32x4 s = z;
            s = MFMA16(qf0, kf0, s);
            s = MFMA16(qf1, kf1, s);
#pragma unroll
            for (int j = 0; j < 4; j++)
                P[bufw][wave * 16 + g * 4 + j][n * 16 + l15] = f2bf(__expf(s[j]) * Rr[j] * civ);
        }
    };

    fill(0, 0);
    __syncthreads();
    int buf = 0;
    for (int kt = 0; kt < LK; kt += 64) {
        bf16x8 pa[4][2];
#pragma unroll
        for (int m = 0; m < 4; m++)
#pragma unroll
            for (int kk = 0; kk < 2; kk++)
                pa[m][kk] = *reinterpret_cast<const bf16x8*>(&P[buf][qg * 64 + m * 16 + l15][kk * 32 + g * 8]);

        if (kt + 64 < LK) fill(buf ^ 1, kt + 64);

#pragma unroll
        for (int nf = 0; nf < 4; nf++) {
            const u16* vrow = wvT + ((size_t)b * DD + n0 + dg * 64 + nf * 16 + l15) * LK + kt;
            bf16x8 bv0 = *reinterpret_cast<const bf16x8*>(vrow + g * 8);
            bf16x8 bv1 = *reinterpret_cast<const bf16x8*>(vrow + 32 + g * 8);
#pragma unroll
            for (int m = 0; m < 4; m++) {
                acc[m][nf] = MFMA16(pa[m][0], bv0, acc[m][nf]);
                acc[m][nf] = MFMA16(pa[m][1], bv1, acc[m][nf]);
            }
        }
        __syncthreads();
        buf ^= 1;
    }
#pragma unroll
    for (int m = 0; m < 4; m++)
#pragma unroll
        for (int nf = 0; nf < 4; nf++)
#pragma unroll
            for (int j = 0; j < 4; j++) {
                int q = q0 + qg * 64 + m * 16 + g * 4 + j;
                int d = n0 + dg * 64 + nf * 16 + l15;
                size_t idx = ((size_t)q * BB + b) * DD + d;
                tout[idx] = f2bf(query[idx] - acc[m][nf][j]);
            }
}

// out[r][n] = relu( t[r,:] @ Wtb[n,:] )   BM=128, BN=128, 4 waves
__global__ __launch_bounds__(256) void k_final(const u16* __restrict__ t, const u16* __restrict__ Wtb,
                                               float* __restrict__ out)
{
    const int r0 = blockIdx.x * 128, n0 = blockIdx.y * 128;
    const int tid = threadIdx.x, wave = tid >> 6, lane = tid & 63, l15 = lane & 15, g = lane >> 4;
    const int qg = wave >> 1, dg = wave & 1;
    f32x4 z = {0.f, 0.f, 0.f, 0.f};
    f32x4 acc[4][4];
#pragma unroll
    for (int m = 0; m < 4; m++)
#pragma unroll
        for (int nf = 0; nf < 4; nf++) acc[m][nf] = z;

#pragma unroll 2
    for (int kt = 0; kt < DD; kt += 32) {
        bf16x8 af[4];
#pragma unroll
        for (int m = 0; m < 4; m++)
            af[m] = *reinterpret_cast<const bf16x8*>(t + (size_t)(r0 + qg * 64 + m * 16 + l15) * DD + kt + g * 8);
#pragma unroll
        for (int nf = 0; nf < 4; nf++) {
            bf16x8 bw = *reinterpret_cast<const bf16x8*>(Wtb + (size_t)(n0 + dg * 64 + nf * 16 + l15) * DD + kt + g * 8);
#pragma unroll
            for (int m = 0; m < 4; m++) acc[m][nf] = MFMA16(af[m], bw, acc[m][nf]);
        }
    }
#pragma unroll
    for (int m = 0; m < 4; m++)
#pragma unroll
        for (int nf = 0; nf < 4; nf++)
#pragma unroll
            for (int j = 0; j < 4; j++)
                out[(size_t)(r0 + qg * 64 + m * 16 + g * 4 + j) * DD + n0 + dg * 64 + nf * 16 + l15] =
                    fmaxf(acc[m][nf][j], 0.f);
}

extern "C" void kernel_launch(void* const* d_in, const int* in_sizes, int n_in,
                              void* d_out, int out_size, void* d_ws, size_t ws_size,
                              hipStream_t stream)
{
    const float* query = (const float*)d_in[0];
    const float* key   = (const float*)d_in[1];
    const float* value = (const float*)d_in[2];
    const float* WK    = (const float*)d_in[3];
    const float* WQ    = (const float*)d_in[4];
    const float* WV    = (const float*)d_in[5];
    const float* Wt    = (const float*)d_in[6];
    float* out = (float*)d_out;

    char* ws = (char*)d_ws;
    u16*   wqb = (u16*)(ws);                                   //  4 MB [B][LQ][64] bf16
    u16*   wkb = (u16*)(ws + (4u << 20));                      //  4 MB [B][LK][64] bf16
    u16*   wvS = (u16*)(ws + (8u << 20));                      // 32 MB [B][512][LK] bf16
    u16*   t   = (u16*)(ws + (40u << 20));                     // 32 MB [LQ][B][512] bf16
    float* Rq  = (float*)(ws + (72u << 20));                   // 128 KB [B][LQ] f32
    float* ci  = (float*)(ws + (72u << 20) + (128u << 10));    // 128 KB [B][LK] f32
    u16*   WQb = (u16*)(ws + (72u << 20) + (256u << 10));      // 64 KB
    u16*   WKb = (u16*)(ws + (72u << 20) + (320u << 10));      // 64 KB
    u16*   WVb = (u16*)(ws + (72u << 20) + (384u << 10));      // 512 KB
    u16*   Wtb = (u16*)(ws + (72u << 20) + (896u << 10));      // 512 KB
    u16*   E   = (u16*)(ws + (74ull << 20));                   // 8 MB * G

    // choose group size (batches per E chunk) by available workspace
    int G = 0;
    const size_t fixed = 74ull << 20;
    for (int g = 16; g >= 1; g >>= 1)
        if (fixed + ((size_t)g << 23) <= ws_size) { G = g; break; }

    k_cvt<<<32, 256, 0, stream>>>(WQ, WQb, DKK * DD);
    k_cvt<<<32, 256, 0, stream>>>(WK, WKb, DKK * DD);
    k_cvt<<<256, 256, 0, stream>>>(WV, WVb, DD * DD);
    k_cvt<<<256, 256, 0, stream>>>(Wt, Wtb, DD * DD);

    k_projqk<<<dim3(LQ / 128, BB), 256, 0, stream>>>(query, WQb, wqb);
    k_projqk<<<dim3(LK / 128, BB), 256, 0, stream>>>(key, WKb, wkb);

    // pass 1: Rq[b][q] = 1/sum_k exp(s)
    k_expsum<<<dim3(LQ / 64, BB), 256, 0, stream>>>(wqb, wkb, nullptr, Rq, 0.f, nullptr, 0);

    if (G > 0) {
        for (int b0 = 0; b0 < BB; b0 += G) {
            // pass 2: ci[b][k] = 1/(eps+sum_q exp*Rq), and E[q][k] = bf16(exp*Rq)
            k_expsum<<<dim3(LK / 64, G), 256, 0, stream>>>(wkb, wqb, Rq, ci, EPSF, E, b0);
            // wvS = (value@WV^T)*ci
            k_projv<<<dim3(LK / 128, DD / 128, G), 256, 0, stream>>>(value, WVb, ci, wvS, b0);
            // t = query - E @ wvS^T
            k_pvgemm<<<64 * G, 256, 0, stream>>>(query, E, wvS, t, b0, G);
        }
    } else {
        k_expsum<<<dim3(LK / 64, BB), 256, 0, stream>>>(wkb, wqb, Rq, ci, EPSF, nullptr, 0);
        k_projv<<<dim3(LK / 128, DD / 128, BB), 256, 0, stream>>>(value, WVb, nullptr, wvS, 0);
        k_pv_fb<<<512, 512, 0, stream>>>(query, wqb, wkb, wvS, Rq, ci, t);
    }

    k_final<<<dim3(256, 4), 256, 0, stream>>>(t, Wtb, out);
}

// Round 6
// 400.968 us; speedup vs baseline: 1.6480x; 1.4399x over previous
//
#include <hip/hip_runtime.h>

#define LQ 2048
#define LK 2048
#define BB 16
#define DD 512
#define DKK 64
#define EPSF 1e-9f

typedef unsigned short u16;
typedef __attribute__((ext_vector_type(8))) short bf16x8;
typedef __attribute__((ext_vector_type(4))) float f32x4;
#define MFMA16(a, b, c) __builtin_amdgcn_mfma_f32_16x16x32_bf16(a, b, c, 0, 0, 0)

__device__ inline u16 f2bf(float f) {
    unsigned int u = __float_as_uint(f);
    u += 0x7fffu + ((u >> 16) & 1u);   // RNE
    return (u16)(u >> 16);
}
__device__ inline bf16x8 cvt8(float4 a, float4 b) {
    bf16x8 r;
    r[0] = (short)f2bf(a.x); r[1] = (short)f2bf(a.y); r[2] = (short)f2bf(a.z); r[3] = (short)f2bf(a.w);
    r[4] = (short)f2bf(b.x); r[5] = (short)f2bf(b.y); r[6] = (short)f2bf(b.z); r[7] = (short)f2bf(b.w);
    return r;
}
// async global->LDS, 16B per lane; LDS dest = wave-uniform base + lane*16
__device__ inline void gload16(const void* g, void* l) {
    __builtin_amdgcn_global_load_lds((const __attribute__((address_space(1))) unsigned int*)g,
                                     (__attribute__((address_space(3))) unsigned int*)l, 16, 0, 0);
}

__global__ __launch_bounds__(256) void k_cvt(const float* __restrict__ src, u16* __restrict__ dst, int n) {
    int i = (blockIdx.x * 256 + threadIdx.x) * 4;
    if (i < n) {
        float4 v = *reinterpret_cast<const float4*>(src + i);
        *reinterpret_cast<ushort4*>(dst + i) = make_ushort4(f2bf(v.x), f2bf(v.y), f2bf(v.z), f2bf(v.w));
    }
}

// y[b][l][dk] = l2norm( x[l,b,:] @ Wb[dk,:] )
__global__ __launch_bounds__(256) void k_projqk(const float* __restrict__ x, const u16* __restrict__ Wb,
                                                u16* __restrict__ y)
{
    const int b = blockIdx.y, r0 = blockIdx.x * 128;
    const int tid = threadIdx.x, wave = tid >> 6, lane = tid & 63, l15 = lane & 15, g = lane >> 4;
    const int rw = r0 + wave * 32;
    f32x4 z = {0.f, 0.f, 0.f, 0.f};
    f32x4 acc[2][4];
#pragma unroll
    for (int m = 0; m < 2; m++)
#pragma unroll
        for (int nf = 0; nf < 4; nf++) acc[m][nf] = z;

    for (int kt = 0; kt < DD; kt += 32) {
        bf16x8 af[2];
#pragma unroll
        for (int m = 0; m < 2; m++) {
            const float* p = x + ((size_t)(rw + 16 * m + l15) * BB + b) * DD + kt + g * 8;
            af[m] = cvt8(*reinterpret_cast<const float4*>(p), *reinterpret_cast<const float4*>(p + 4));
        }
#pragma unroll
        for (int nf = 0; nf < 4; nf++) {
            bf16x8 bf_ = *reinterpret_cast<const bf16x8*>(Wb + (size_t)(nf * 16 + l15) * DD + kt + g * 8);
            acc[0][nf] = MFMA16(af[0], bf_, acc[0][nf]);
            acc[1][nf] = MFMA16(af[1], bf_, acc[1][nf]);
        }
    }
#pragma unroll
    for (int m = 0; m < 2; m++) {
        float rn[4];
#pragma unroll
        for (int j = 0; j < 4; j++) {
            float t2 = acc[m][0][j] * acc[m][0][j] + acc[m][1][j] * acc[m][1][j]
                     + acc[m][2][j] * acc[m][2][j] + acc[m][3][j] * acc[m][3][j];
            t2 += __shfl_xor(t2, 1, 64);
            t2 += __shfl_xor(t2, 2, 64);
            t2 += __shfl_xor(t2, 4, 64);
            t2 += __shfl_xor(t2, 8, 64);
            rn[j] = 1.f / fmaxf(sqrtf(t2), 1e-12f);
        }
#pragma unroll
        for (int nf = 0; nf < 4; nf++)
#pragma unroll
            for (int j = 0; j < 4; j++) {
                int q = rw + 16 * m + g * 4 + j;
                y[((size_t)b * LQ + q) * DKK + nf * 16 + l15] = f2bf(acc[m][nf][j] * rn[j]);
            }
    }
}

// wvS[b][d][k] = (value[k,b,:] @ WVb[d,:]) * (ci ? ci[b][k] : 1)
__global__ __launch_bounds__(256) void k_projv(const float* __restrict__ value, const u16* __restrict__ WVb,
                                               const float* __restrict__ ci, u16* __restrict__ wvS, int b0)
{
    const int b = b0 + blockIdx.z, k0 = blockIdx.x * 128, n0 = blockIdx.y * 128;
    const int tid = threadIdx.x, lane = tid & 63, l15 = lane & 15, g = lane >> 4;
    const int wave = tid >> 6, qg = wave >> 1, dg = wave & 1;
    __shared__ __align__(16) u16 A[2][128][40];
    f32x4 z = {0.f, 0.f, 0.f, 0.f};
    f32x4 acc[4][4];
#pragma unroll
    for (int m = 0; m < 4; m++)
#pragma unroll
        for (int nf = 0; nf < 4; nf++) acc[m][nf] = z;

    const int sr = tid >> 1, sc = (tid & 1) * 16;
    auto stage = [&](int bufw, int kt) {
        const float* p = value + ((size_t)(k0 + sr) * BB + b) * DD + kt + sc;
        *reinterpret_cast<bf16x8*>(&A[bufw][sr][sc]) =
            cvt8(*reinterpret_cast<const float4*>(p), *reinterpret_cast<const float4*>(p + 4));
        *reinterpret_cast<bf16x8*>(&A[bufw][sr][sc + 8]) =
            cvt8(*reinterpret_cast<const float4*>(p + 8), *reinterpret_cast<const float4*>(p + 12));
    };
    stage(0, 0);
    __syncthreads();
    int buf = 0;
    for (int kt = 0; kt < DD; kt += 32) {
        if (kt + 32 < DD) stage(buf ^ 1, kt + 32);
        bf16x8 af[4];
#pragma unroll
        for (int m = 0; m < 4; m++)
            af[m] = *reinterpret_cast<const bf16x8*>(&A[buf][qg * 64 + m * 16 + l15][g * 8]);
#pragma unroll
        for (int nf = 0; nf < 4; nf++) {
            bf16x8 bw = *reinterpret_cast<const bf16x8*>(WVb + (size_t)(n0 + dg * 64 + nf * 16 + l15) * DD + kt + g * 8);
#pragma unroll
            for (int m = 0; m < 4; m++) acc[m][nf] = MFMA16(af[m], bw, acc[m][nf]);
        }
        __syncthreads();
        buf ^= 1;
    }
#pragma unroll
    for (int m = 0; m < 4; m++) {
        float cv[4] = {1.f, 1.f, 1.f, 1.f};
        if (ci) {
#pragma unroll
            for (int j = 0; j < 4; j++)
                cv[j] = ci[(size_t)b * LK + k0 + qg * 64 + m * 16 + g * 4 + j];
        }
#pragma unroll
        for (int nf = 0; nf < 4; nf++) {
            int d = n0 + dg * 64 + nf * 16 + l15;
            size_t base = ((size_t)b * DD + d) * LK + k0 + qg * 64 + m * 16 + g * 4;
            *reinterpret_cast<ushort4*>(wvS + base) =
                make_ushort4(f2bf(acc[m][nf][0] * cv[0]), f2bf(acc[m][nf][1] * cv[1]),
                             f2bf(acc[m][nf][2] * cv[2]), f2bf(acc[m][nf][3] * cv[3]));
        }
    }
}

// outv[row] = 1/(eps + sum_cols exp(s)*w[col]);  optionally E[col][row] = bf16(exp(s)*w[col])
// 128 rows/block, wave owns 32 rows (2 frags)
__global__ __launch_bounds__(256) void k_expsum(const u16* __restrict__ A, const u16* __restrict__ Bm,
                                                const float* __restrict__ wcol, float* __restrict__ outv,
                                                float eps, u16* __restrict__ E, int b0)
{
    const int b = b0 + blockIdx.y, r0 = blockIdx.x * 128;
    const int tid = threadIdx.x, wave = tid >> 6, lane = tid & 63, l15 = lane & 15, g = lane >> 4;
    f32x4 z = {0.f, 0.f, 0.f, 0.f};
    u16* Eb = E ? (E + (size_t)blockIdx.y * LQ * LK) : nullptr;

    bf16x8 af[2][2];
#pragma unroll
    for (int m = 0; m < 2; m++) {
        const u16* ar = A + ((size_t)b * LK + r0 + wave * 32 + m * 16 + l15) * DKK;
        af[m][0] = *reinterpret_cast<const bf16x8*>(ar + g * 8);
        af[m][1] = *reinterpret_cast<const bf16x8*>(ar + 32 + g * 8);
    }
    float acc[2][4] = {{0.f, 0.f, 0.f, 0.f}, {0.f, 0.f, 0.f, 0.f}};

    for (int ct = 0; ct < LK; ct += 64) {
#pragma unroll
        for (int n = 0; n < 4; n++) {
            int col = ct + n * 16;
            const u16* br = Bm + ((size_t)b * LK + col + l15) * DKK;
            bf16x8 b0v = *reinterpret_cast<const bf16x8*>(br + g * 8);
            bf16x8 b1v = *reinterpret_cast<const bf16x8*>(br + 32 + g * 8);
            float w = wcol ? wcol[(size_t)b * LK + col + l15] : 1.f;
#pragma unroll
            for (int m = 0; m < 2; m++) {
                f32x4 s = z;
                s = MFMA16(af[m][0], b0v, s);
                s = MFMA16(af[m][1], b1v, s);
                float pe[4];
#pragma unroll
                for (int j = 0; j < 4; j++) { pe[j] = __expf(s[j]) * w; acc[m][j] += pe[j]; }
                if (Eb) {
                    size_t idx = (size_t)(col + l15) * LK + r0 + wave * 32 + m * 16 + g * 4;
                    *reinterpret_cast<ushort4*>(Eb + idx) =
                        make_ushort4(f2bf(pe[0]), f2bf(pe[1]), f2bf(pe[2]), f2bf(pe[3]));
                }
            }
        }
    }
#pragma unroll
    for (int m = 0; m < 2; m++)
#pragma unroll
        for (int j = 0; j < 4; j++) {
            float v = acc[m][j];
            v += __shfl_xor(v, 1, 64);
            v += __shfl_xor(v, 2, 64);
            v += __shfl_xor(v, 4, 64);
            v += __shfl_xor(v, 8, 64);
            if (l15 == 0) outv[(size_t)b * LK + r0 + wave * 32 + m * 16 + g * 4 + j] = 1.f / (eps + v);
        }
}

// t[q,b,:] = query - E @ wvS^T.  128x128 tile, BK=64, LDS-staged via global_load_lds,
// XOR-swizzle (row&7)<<4 applied on global source + ds_read (rule 21).
__global__ __launch_bounds__(256, 3) void k_pvgemm(const float* __restrict__ query,
                                                   const u16* __restrict__ E,
                                                   const u16* __restrict__ wvS,
                                                   u16* __restrict__ tout, int b0, int G)
{
    const int i = blockIdx.x;
    int bl, tile;
    if (G == 16) { bl = (i & 7) + 8 * (i >> 9); tile = (i >> 3) & 63; }  // XCD-pinned batches
    else         { bl = i % G; tile = i / G; }
    const int b = b0 + bl;
    const int q0 = (tile >> 2) * 128, n0 = (tile & 3) * 128;
    const int tid = threadIdx.x, wv = tid >> 6, lane = tid & 63, l15 = lane & 15, g = lane >> 4;
    const int qg = wv >> 1, dg = wv & 1;

    __shared__ __align__(16) u16 As[128 * 64], Bs[128 * 64];

    const u16* Eb = E + (size_t)bl * LQ * LK;
    const u16* Vb = wvS + (size_t)b * DD * LK;

    // staging source: lane covers row srow(+p*32), 16B at swizzled col byte
    const int srow = wv * 8 + (lane >> 3);
    const int scb = ((lane & 7) * 16) ^ ((srow & 7) << 4);
    const char* gA = (const char*)(Eb + (size_t)(q0 + srow) * LK) + scb;
    const char* gB = (const char*)(Vb + (size_t)(n0 + srow) * LK) + scb;
    const size_t rstep = (size_t)32 * LK * 2;

    f32x4 z = {0.f, 0.f, 0.f, 0.f};
    f32x4 acc[4][4];
#pragma unroll
    for (int m = 0; m < 4; m++)
#pragma unroll
        for (int nf = 0; nf < 4; nf++) acc[m][nf] = z;

#pragma unroll
    for (int p = 0; p < 4; ++p) {
        gload16(gA + p * rstep, (char*)As + p * 4096 + wv * 1024);
        gload16(gB + p * rstep, (char*)Bs + p * 4096 + wv * 1024);
    }

    for (int t = 0; t < LK / 64; ++t) {
        __syncthreads();                       // vmcnt(0): tile t landed
        bf16x8 af[4][2], bv[4][2];
#pragma unroll
        for (int m = 0; m < 4; m++) {
            int row = qg * 64 + m * 16 + l15;
            const char* rp = (const char*)As + row * 128;
            int x = (row & 7) << 4;
#pragma unroll
            for (int kk = 0; kk < 2; kk++)
                af[m][kk] = *reinterpret_cast<const bf16x8*>(rp + ((kk * 64 + g * 16) ^ x));
        }
#pragma unroll
        for (int nf = 0; nf < 4; nf++) {
            int row = dg * 64 + nf * 16 + l15;
            const char* rp = (const char*)Bs + row * 128;
            int x = (row & 7) << 4;
#pragma unroll
            for (int kk = 0; kk < 2; kk++)
                bv[nf][kk] = *reinterpret_cast<const bf16x8*>(rp + ((kk * 64 + g * 16) ^ x));
        }
        __syncthreads();                       // lgkm drained: LDS free
        if (t + 1 < LK / 64) {
            int ktb = (t + 1) * 128;
#pragma unroll
            for (int p = 0; p < 4; ++p) {      // next tile flies under MFMAs
                gload16(gA + p * rstep + ktb, (char*)As + p * 4096 + wv * 1024);
                gload16(gB + p * rstep + ktb, (char*)Bs + p * 4096 + wv * 1024);
            }
        }
#pragma unroll
        for (int nf = 0; nf < 4; nf++)
#pragma unroll
            for (int m = 0; m < 4; m++) {
                acc[m][nf] = MFMA16(af[m][0], bv[nf][0], acc[m][nf]);
                acc[m][nf] = MFMA16(af[m][1], bv[nf][1], acc[m][nf]);
            }
    }
#pragma unroll
    for (int m = 0; m < 4; m++)
#pragma unroll
        for (int nf = 0; nf < 4; nf++)
#pragma unroll
            for (int j = 0; j < 4; j++) {
                int q = q0 + qg * 64 + m * 16 + g * 4 + j;
                int d = n0 + dg * 64 + nf * 16 + l15;
                size_t idx = ((size_t)q * BB + b) * DD + d;
                tout[idx] = f2bf(query[idx] - acc[m][nf][j]);
            }
}

// fallback (R3-proven): inline-recompute PV
__global__ __launch_bounds__(512) void k_pv_fb(const float* __restrict__ query, const u16* __restrict__ wqb,
                                               const u16* __restrict__ wkb, const u16* __restrict__ wvT,
                                               const float* __restrict__ Rq, const float* __restrict__ ci,
                                               u16* __restrict__ tout)
{
    const int i = blockIdx.x;
    const int b = (i & 7) + 8 * ((i >> 3) & 1);
    const int rest = i >> 4;
    const int q0 = (rest & 15) * 128, n0 = (rest >> 4) * 256;
    const int tid = threadIdx.x, wave = tid >> 6, lane = tid & 63, l15 = lane & 15, g = lane >> 4;
    const int qg = wave >> 2, dg = wave & 3;
    __shared__ __align__(16) u16 P[2][128][72];
    f32x4 z = {0.f, 0.f, 0.f, 0.f};

    const u16* qrow = wqb + ((size_t)b * LQ + q0 + wave * 16 + l15) * DKK;
    bf16x8 qf0 = *reinterpret_cast<const bf16x8*>(qrow + g * 8);
    bf16x8 qf1 = *reinterpret_cast<const bf16x8*>(qrow + 32 + g * 8);
    float Rr[4];
#pragma unroll
    for (int j = 0; j < 4; j++) Rr[j] = Rq[(size_t)b * LQ + q0 + wave * 16 + g * 4 + j];

    f32x4 acc[4][4];
#pragma unroll
    for (int m = 0; m < 4; m++)
#pragma unroll
        for (int nf = 0; nf < 4; nf++) acc[m][nf] = z;

    auto fill = [&](int bufw, int kt) {
#pragma unroll
        for (int n = 0; n < 4; n++) {
            const u16* krow = wkb + ((size_t)b * LK + kt + n * 16 + l15) * DKK;
            bf16x8 kf0 = *reinterpret_cast<const bf16x8*>(krow + g * 8);
            bf16x8 kf1 = *reinterpret_cast<const bf16x8*>(krow + 32 + g * 8);
            float civ = ci[(size_t)b * LK + kt + n * 16 + l15];
            f32x4 s = z;
            s = MFMA16(qf0, kf0, s);
            s = MFMA16(qf1, kf1, s);
#pragma unroll
            for (int j = 0; j < 4; j++)
                P[bufw][wave * 16 + g * 4 + j][n * 16 + l15] = f2bf(__expf(s[j]) * Rr[j] * civ);
        }
    };

    fill(0, 0);
    __syncthreads();
    int buf = 0;
    for (int kt = 0; kt < LK; kt += 64) {
        bf16x8 pa[4][2];
#pragma unroll
        for (int m = 0; m < 4; m++)
#pragma unroll
            for (int kk = 0; kk < 2; kk++)
                pa[m][kk] = *reinterpret_cast<const bf16x8*>(&P[buf][qg * 64 + m * 16 + l15][kk * 32 + g * 8]);

        if (kt + 64 < LK) fill(buf ^ 1, kt + 64);

#pragma unroll
        for (int nf = 0; nf < 4; nf++) {
            const u16* vrow = wvT + ((size_t)b * DD + n0 + dg * 64 + nf * 16 + l15) * LK + kt;
            bf16x8 bv0 = *reinterpret_cast<const bf16x8*>(vrow + g * 8);
            bf16x8 bv1 = *reinterpret_cast<const bf16x8*>(vrow + 32 + g * 8);
#pragma unroll
            for (int m = 0; m < 4; m++) {
                acc[m][nf] = MFMA16(pa[m][0], bv0, acc[m][nf]);
                acc[m][nf] = MFMA16(pa[m][1], bv1, acc[m][nf]);
            }
        }
        __syncthreads();
        buf ^= 1;
    }
#pragma unroll
    for (int m = 0; m < 4; m++)
#pragma unroll
        for (int nf = 0; nf < 4; nf++)
#pragma unroll
            for (int j = 0; j < 4; j++) {
                int q = q0 + qg * 64 + m * 16 + g * 4 + j;
                int d = n0 + dg * 64 + nf * 16 + l15;
                size_t idx = ((size_t)q * BB + b) * DD + d;
                tout[idx] = f2bf(query[idx] - acc[m][nf][j]);
            }
}

// out = relu( t @ Wtb^T ): 128x128 tile, same staged structure, K=512
__global__ __launch_bounds__(256, 3) void k_final(const u16* __restrict__ t, const u16* __restrict__ Wtb,
                                                  float* __restrict__ out)
{
    const int r0 = blockIdx.x * 128, n0 = blockIdx.y * 128;
    const int tid = threadIdx.x, wv = tid >> 6, lane = tid & 63, l15 = lane & 15, g = lane >> 4;
    const int qg = wv >> 1, dg = wv & 1;

    __shared__ __align__(16) u16 As[128 * 64], Bs[128 * 64];

    const int srow = wv * 8 + (lane >> 3);
    const int scb = ((lane & 7) * 16) ^ ((srow & 7) << 4);
    const char* gA = (const char*)(t + (size_t)(r0 + srow) * DD) + scb;
    const char* gB = (const char*)(Wtb + (size_t)(n0 + srow) * DD) + scb;
    const size_t rstep = (size_t)32 * DD * 2;

    f32x4 z = {0.f, 0.f, 0.f, 0.f};
    f32x4 acc[4][4];
#pragma unroll
    for (int m = 0; m < 4; m++)
#pragma unroll
        for (int nf = 0; nf < 4; nf++) acc[m][nf] = z;

#pragma unroll
    for (int p = 0; p < 4; ++p) {
        gload16(gA + p * rstep, (char*)As + p * 4096 + wv * 1024);
        gload16(gB + p * rstep, (char*)Bs + p * 4096 + wv * 1024);
    }

    for (int tt = 0; tt < DD / 64; ++tt) {
        __syncthreads();
        bf16x8 af[4][2], bv[4][2];
#pragma unroll
        for (int m = 0; m < 4; m++) {
            int row = qg * 64 + m * 16 + l15;
            const char* rp = (const char*)As + row * 128;
            int x = (row & 7) << 4;
#pragma unroll
            for (int kk = 0; kk < 2; kk++)
                af[m][kk] = *reinterpret_cast<const bf16x8*>(rp + ((kk * 64 + g * 16) ^ x));
        }
#pragma unroll
        for (int nf = 0; nf < 4; nf++) {
            int row = dg * 64 + nf * 16 + l15;
            const char* rp = (const char*)Bs + row * 128;
            int x = (row & 7) << 4;
#pragma unroll
            for (int kk = 0; kk < 2; kk++)
                bv[nf][kk] = *reinterpret_cast<const bf16x8*>(rp + ((kk * 64 + g * 16) ^ x));
        }
        __syncthreads();
        if (tt + 1 < DD / 64) {
            int ktb = (tt + 1) * 128;
#pragma unroll
            for (int p = 0; p < 4; ++p) {
                gload16(gA + p * rstep + ktb, (char*)As + p * 4096 + wv * 1024);
                gload16(gB + p * rstep + ktb, (char*)Bs + p * 4096 + wv * 1024);
            }
        }
#pragma unroll
        for (int nf = 0; nf < 4; nf++)
#pragma unroll
            for (int m = 0; m < 4; m++) {
                acc[m][nf] = MFMA16(af[m][0], bv[nf][0], acc[m][nf]);
                acc[m][nf] = MFMA16(af[m][1], bv[nf][1], acc[m][nf]);
            }
    }
#pragma unroll
    for (int m = 0; m < 4; m++)
#pragma unroll
        for (int nf = 0; nf < 4; nf++)
#pragma unroll
            for (int j = 0; j < 4; j++)
                out[(size_t)(r0 + qg * 64 + m * 16 + g * 4 + j) * DD + n0 + dg * 64 + nf * 16 + l15] =
                    fmaxf(acc[m][nf][j], 0.f);
}

extern "C" void kernel_launch(void* const* d_in, const int* in_sizes, int n_in,
                              void* d_out, int out_size, void* d_ws, size_t ws_size,
                              hipStream_t stream)
{
    const float* query = (const float*)d_in[0];
    const float* key   = (const float*)d_in[1];
    const float* value = (const float*)d_in[2];
    const float* WK    = (const float*)d_in[3];
    const float* WQ    = (const float*)d_in[4];
    const float* WV    = (const float*)d_in[5];
    const float* Wt    = (const float*)d_in[6];
    float* out = (float*)d_out;

    char* ws = (char*)d_ws;
    u16*   wqb = (u16*)(ws);                                   //  4 MB [B][LQ][64] bf16
    u16*   wkb = (u16*)(ws + (4u << 20));                      //  4 MB [B][LK][64] bf16
    u16*   wvS = (u16*)(ws + (8u << 20));                      // 32 MB [B][512][LK] bf16
    u16*   t   = (u16*)(ws + (40u << 20));                     // 32 MB [LQ][B][512] bf16
    float* Rq  = (float*)(ws + (72u << 20));                   // 128 KB [B][LQ] f32
    float* ci  = (float*)(ws + (72u << 20) + (128u << 10));    // 128 KB [B][LK] f32
    u16*   WQb = (u16*)(ws + (72u << 20) + (256u << 10));      // 64 KB
    u16*   WKb = (u16*)(ws + (72u << 20) + (320u << 10));      // 64 KB
    u16*   WVb = (u16*)(ws + (72u << 20) + (384u << 10));      // 512 KB
    u16*   Wtb = (u16*)(ws + (72u << 20) + (896u << 10));      // 512 KB
    u16*   E   = (u16*)(ws + (74ull << 20));                   // 8 MB * G

    int G = 0;
    const size_t fixed = 74ull << 20;
    for (int g = 16; g >= 1; g >>= 1)
        if (fixed + ((size_t)g << 23) <= ws_size) { G = g; break; }

    k_cvt<<<32, 256, 0, stream>>>(WQ, WQb, DKK * DD);
    k_cvt<<<32, 256, 0, stream>>>(WK, WKb, DKK * DD);
    k_cvt<<<256, 256, 0, stream>>>(WV, WVb, DD * DD);
    k_cvt<<<256, 256, 0, stream>>>(Wt, Wtb, DD * DD);

    k_projqk<<<dim3(LQ / 128, BB), 256, 0, stream>>>(query, WQb, wqb);
    k_projqk<<<dim3(LK / 128, BB), 256, 0, stream>>>(key, WKb, wkb);

    // pass 1: Rq[b][q] = 1/sum_k exp(s)
    k_expsum<<<dim3(LQ / 128, BB), 256, 0, stream>>>(wqb, wkb, nullptr, Rq, 0.f, nullptr, 0);

    if (G > 0) {
        for (int b0 = 0; b0 < BB; b0 += G) {
            k_expsum<<<dim3(LK / 128, G), 256, 0, stream>>>(wkb, wqb, Rq, ci, EPSF, E, b0);
            k_projv<<<dim3(LK / 128, DD / 128, G), 256, 0, stream>>>(value, WVb, ci, wvS, b0);
            k_pvgemm<<<64 * G, 256, 0, stream>>>(query, E, wvS, t, b0, G);
        }
    } else {
        k_expsum<<<dim3(LK / 128, BB), 256, 0, stream>>>(wkb, wqb, Rq, ci, EPSF, nullptr, 0);
        k_projv<<<dim3(LK / 128, DD / 128, BB), 256, 0, stream>>>(value, WVb, nullptr, wvS, 0);
        k_pv_fb<<<512, 512, 0, stream>>>(query, wqb, wkb, wvS, Rq, ci, t);
    }

    k_final<<<dim3(LQ * BB / 128, DD / 128), 256, 0, stream>>>(t, Wtb, out);
}

// Round 7
// 350.840 us; speedup vs baseline: 1.8835x; 1.1429x over previous
//
#include <hip/hip_runtime.h>

#define LQ 2048
#define LK 2048
#define BB 16
#define DD 512
#define DKK 64
#define EPSF 1e-9f

typedef unsigned short u16;
typedef unsigned char u8;
typedef long i64;
typedef __attribute__((ext_vector_type(8))) short bf16x8;
typedef __attribute__((ext_vector_type(4))) float f32x4;
#define MFMA16(a, b, c) __builtin_amdgcn_mfma_f32_16x16x32_bf16(a, b, c, 0, 0, 0)
#define MFMAF8(a, b, c) __builtin_amdgcn_mfma_f32_16x16x32_fp8_fp8(a, b, c, 0, 0, 0)
#define ESCALE 1024.0f
#define ESCALE_INV 0.0009765625f

__device__ inline u16 f2bf(float f) {
    unsigned int u = __float_as_uint(f);
    u += 0x7fffu + ((u >> 16) & 1u);   // RNE
    return (u16)(u >> 16);
}
__device__ inline bf16x8 cvt8(float4 a, float4 b) {
    bf16x8 r;
    r[0] = (short)f2bf(a.x); r[1] = (short)f2bf(a.y); r[2] = (short)f2bf(a.z); r[3] = (short)f2bf(a.w);
    r[4] = (short)f2bf(b.x); r[5] = (short)f2bf(b.y); r[6] = (short)f2bf(b.z); r[7] = (short)f2bf(b.w);
    return r;
}
// pack 4 f32 -> 4 fp8 e4m3 bytes
__device__ inline int pk_fp8x4(float a, float b, float c, float d) {
    int r = __builtin_amdgcn_cvt_pk_fp8_f32(a, b, 0, false);
    r = __builtin_amdgcn_cvt_pk_fp8_f32(c, d, r, true);
    return r;
}
// async global->LDS, 16B per lane; LDS dest = wave-uniform base + lane*16
__device__ inline void gload16(const void* g, void* l) {
    __builtin_amdgcn_global_load_lds((const __attribute__((address_space(1))) unsigned int*)g,
                                     (__attribute__((address_space(3))) unsigned int*)l, 16, 0, 0);
}

__global__ __launch_bounds__(256) void k_cvt(const float* __restrict__ src, u16* __restrict__ dst, int n) {
    int i = (blockIdx.x * 256 + threadIdx.x) * 4;
    if (i < n) {
        float4 v = *reinterpret_cast<const float4*>(src + i);
        *reinterpret_cast<ushort4*>(dst + i) = make_ushort4(f2bf(v.x), f2bf(v.y), f2bf(v.z), f2bf(v.w));
    }
}

// fused q/k projection + l2norm.  z=0: query->wq, z=1: key->wk.  BM=64 (wave owns 16 rows)
__global__ __launch_bounds__(256) void k_projqk(const float* __restrict__ xq, const float* __restrict__ xk,
                                                const u16* __restrict__ Wq, const u16* __restrict__ Wk,
                                                u16* __restrict__ yq, u16* __restrict__ yk)
{
    const float* x = blockIdx.z ? xk : xq;
    const u16* Wb = blockIdx.z ? Wk : Wq;
    u16* y = blockIdx.z ? yk : yq;
    const int b = blockIdx.y, r0 = blockIdx.x * 64;
    const int tid = threadIdx.x, wave = tid >> 6, lane = tid & 63, l15 = lane & 15, g = lane >> 4;
    const int rw = r0 + wave * 16;
    f32x4 z = {0.f, 0.f, 0.f, 0.f};
    f32x4 acc[4];
#pragma unroll
    for (int nf = 0; nf < 4; nf++) acc[nf] = z;

    for (int kt = 0; kt < DD; kt += 32) {
        const float* p = x + ((size_t)(rw + l15) * BB + b) * DD + kt + g * 8;
        bf16x8 af = cvt8(*reinterpret_cast<const float4*>(p), *reinterpret_cast<const float4*>(p + 4));
#pragma unroll
        for (int nf = 0; nf < 4; nf++) {
            bf16x8 bf_ = *reinterpret_cast<const bf16x8*>(Wb + (size_t)(nf * 16 + l15) * DD + kt + g * 8);
            acc[nf] = MFMA16(af, bf_, acc[nf]);
        }
    }
    float rn[4];
#pragma unroll
    for (int j = 0; j < 4; j++) {
        float t2 = acc[0][j] * acc[0][j] + acc[1][j] * acc[1][j]
                 + acc[2][j] * acc[2][j] + acc[3][j] * acc[3][j];
        t2 += __shfl_xor(t2, 1, 64);
        t2 += __shfl_xor(t2, 2, 64);
        t2 += __shfl_xor(t2, 4, 64);
        t2 += __shfl_xor(t2, 8, 64);
        rn[j] = 1.f / fmaxf(sqrtf(t2), 1e-12f);
    }
#pragma unroll
    for (int nf = 0; nf < 4; nf++)
#pragma unroll
        for (int j = 0; j < 4; j++) {
            int q = rw + g * 4 + j;
            y[((size_t)b * LQ + q) * DKK + nf * 16 + l15] = f2bf(acc[nf][j] * rn[j]);
        }
}

// wvS[b][d][k] = fp8( (value[k,b,:] @ WVb[d,:]) * ci[b][k] )
__global__ __launch_bounds__(256) void k_projv(const float* __restrict__ value, const u16* __restrict__ WVb,
                                               const float* __restrict__ ci, u8* __restrict__ wvS, int b0)
{
    const int b = b0 + blockIdx.z, k0 = blockIdx.x * 128, n0 = blockIdx.y * 128;
    const int tid = threadIdx.x, lane = tid & 63, l15 = lane & 15, g = lane >> 4;
    const int wave = tid >> 6, qg = wave >> 1, dg = wave & 1;
    __shared__ __align__(16) u16 A[2][128][40];
    f32x4 z = {0.f, 0.f, 0.f, 0.f};
    f32x4 acc[4][4];
#pragma unroll
    for (int m = 0; m < 4; m++)
#pragma unroll
        for (int nf = 0; nf < 4; nf++) acc[m][nf] = z;

    const int sr = tid >> 1, sc = (tid & 1) * 16;
    auto stage = [&](int bufw, int kt) {
        const float* p = value + ((size_t)(k0 + sr) * BB + b) * DD + kt + sc;
        *reinterpret_cast<bf16x8*>(&A[bufw][sr][sc]) =
            cvt8(*reinterpret_cast<const float4*>(p), *reinterpret_cast<const float4*>(p + 4));
        *reinterpret_cast<bf16x8*>(&A[bufw][sr][sc + 8]) =
            cvt8(*reinterpret_cast<const float4*>(p + 8), *reinterpret_cast<const float4*>(p + 12));
    };
    stage(0, 0);
    __syncthreads();
    int buf = 0;
    for (int kt = 0; kt < DD; kt += 32) {
        if (kt + 32 < DD) stage(buf ^ 1, kt + 32);
        bf16x8 af[4];
#pragma unroll
        for (int m = 0; m < 4; m++)
            af[m] = *reinterpret_cast<const bf16x8*>(&A[buf][qg * 64 + m * 16 + l15][g * 8]);
#pragma unroll
        for (int nf = 0; nf < 4; nf++) {
            bf16x8 bw = *reinterpret_cast<const bf16x8*>(WVb + (size_t)(n0 + dg * 64 + nf * 16 + l15) * DD + kt + g * 8);
#pragma unroll
            for (int m = 0; m < 4; m++) acc[m][nf] = MFMA16(af[m], bw, acc[m][nf]);
        }
        __syncthreads();
        buf ^= 1;
    }
#pragma unroll
    for (int m = 0; m < 4; m++) {
        float cv[4];
#pragma unroll
        for (int j = 0; j < 4; j++)
            cv[j] = ci[(size_t)b * LK + k0 + qg * 64 + m * 16 + g * 4 + j];
#pragma unroll
        for (int nf = 0; nf < 4; nf++) {
            int d = n0 + dg * 64 + nf * 16 + l15;
            size_t base = ((size_t)b * DD + d) * LK + k0 + qg * 64 + m * 16 + g * 4;
            *reinterpret_cast<int*>(wvS + base) =
                pk_fp8x4(acc[m][nf][0] * cv[0], acc[m][nf][1] * cv[1],
                         acc[m][nf][2] * cv[2], acc[m][nf][3] * cv[3]);
        }
    }
}

// outv[row] = 1/(eps + sum_cols exp(s)*w[col]);  optionally E[col][row] = fp8(exp(s)*w[col]*1024)
__global__ __launch_bounds__(256) void k_expsum(const u16* __restrict__ A, const u16* __restrict__ Bm,
                                                const float* __restrict__ wcol, float* __restrict__ outv,
                                                float eps, u8* __restrict__ E, int b0)
{
    const int b = b0 + blockIdx.y, r0 = blockIdx.x * 128;
    const int tid = threadIdx.x, wave = tid >> 6, lane = tid & 63, l15 = lane & 15, g = lane >> 4;
    f32x4 z = {0.f, 0.f, 0.f, 0.f};
    u8* Eb = E ? (E + (size_t)blockIdx.y * LQ * LK) : nullptr;

    bf16x8 af[2][2];
#pragma unroll
    for (int m = 0; m < 2; m++) {
        const u16* ar = A + ((size_t)b * LK + r0 + wave * 32 + m * 16 + l15) * DKK;
        af[m][0] = *reinterpret_cast<const bf16x8*>(ar + g * 8);
        af[m][1] = *reinterpret_cast<const bf16x8*>(ar + 32 + g * 8);
    }
    float acc[2][4] = {{0.f, 0.f, 0.f, 0.f}, {0.f, 0.f, 0.f, 0.f}};

    for (int ct = 0; ct < LK; ct += 64) {
#pragma unroll
        for (int n = 0; n < 4; n++) {
            int col = ct + n * 16;
            const u16* br = Bm + ((size_t)b * LK + col + l15) * DKK;
            bf16x8 b0v = *reinterpret_cast<const bf16x8*>(br + g * 8);
            bf16x8 b1v = *reinterpret_cast<const bf16x8*>(br + 32 + g * 8);
            float w = wcol ? wcol[(size_t)b * LK + col + l15] : 1.f;
#pragma unroll
            for (int m = 0; m < 2; m++) {
                f32x4 s = z;
                s = MFMA16(af[m][0], b0v, s);
                s = MFMA16(af[m][1], b1v, s);
                float pe[4];
#pragma unroll
                for (int j = 0; j < 4; j++) { pe[j] = __expf(s[j]) * w; acc[m][j] += pe[j]; }
                if (Eb) {
                    size_t idx = (size_t)(col + l15) * LK + r0 + wave * 32 + m * 16 + g * 4;
                    *reinterpret_cast<int*>(Eb + idx) =
                        pk_fp8x4(pe[0] * ESCALE, pe[1] * ESCALE, pe[2] * ESCALE, pe[3] * ESCALE);
                }
            }
        }
    }
#pragma unroll
    for (int m = 0; m < 2; m++)
#pragma unroll
        for (int j = 0; j < 4; j++) {
            float v = acc[m][j];
            v += __shfl_xor(v, 1, 64);
            v += __shfl_xor(v, 2, 64);
            v += __shfl_xor(v, 4, 64);
            v += __shfl_xor(v, 8, 64);
            if (l15 == 0) outv[(size_t)b * LK + r0 + wave * 32 + m * 16 + g * 4 + j] = 1.f / (eps + v);
        }
}

// t[q,b,:] = query - (E @ wvS^T)/1024.  fp8 GEMM: 128x128 tile, BK=128, LDS-staged,
// 16B-granular XOR swizzle ((row&7)<<4) applied on global source + ds_read (rule 21).
__global__ __launch_bounds__(256, 3) void k_pvgemm(const float* __restrict__ query,
                                                   const u8* __restrict__ E,
                                                   const u8* __restrict__ wvS,
                                                   u16* __restrict__ tout, int b0, int G)
{
    const int i = blockIdx.x;
    int bl, tile;
    if (G == 16) { bl = (i & 7) + 8 * (i >> 9); tile = (i >> 3) & 63; }  // XCD-pinned batches
    else         { bl = i % G; tile = i / G; }
    const int b = b0 + bl;
    const int q0 = (tile >> 2) * 128, n0 = (tile & 3) * 128;
    const int tid = threadIdx.x, wv = tid >> 6, lane = tid & 63, l15 = lane & 15, g = lane >> 4;
    const int qg = wv >> 1, dg = wv & 1;

    __shared__ __align__(16) char As[16384], Bs[16384];   // 128 rows x 128B fp8 each

    const u8* Eb = E + (size_t)bl * LQ * LK;
    const u8* Vb = wvS + (size_t)b * DD * LK;

    const int srow = wv * 8 + (lane >> 3);
    const int scb = ((lane & 7) * 16) ^ ((srow & 7) << 4);
    const char* gA = (const char*)Eb + (size_t)(q0 + srow) * LK + scb;
    const char* gB = (const char*)Vb + (size_t)(n0 + srow) * LK + scb;
    const size_t rstep = (size_t)32 * LK;

    f32x4 z = {0.f, 0.f, 0.f, 0.f};
    f32x4 acc[4][4];
#pragma unroll
    for (int m = 0; m < 4; m++)
#pragma unroll
        for (int nf = 0; nf < 4; nf++) acc[m][nf] = z;

    auto stage = [&](int t) {
#pragma unroll
        for (int p = 0; p < 4; ++p) {
            gload16(gA + p * rstep + t * 128, (char*)As + p * 4096 + wv * 1024);
            gload16(gB + p * rstep + t * 128, (char*)Bs + p * 4096 + wv * 1024);
        }
    };
    stage(0);

    for (int t = 0; t < LK / 128; ++t) {
        __syncthreads();                       // vmcnt(0): tile t landed
        i64 af[4][4], bv[4][4];
#pragma unroll
        for (int m = 0; m < 4; m++) {
            int row = qg * 64 + m * 16 + l15;
            const char* rp = (const char*)As + row * 128;
            int x = (row & 7) << 4;
#pragma unroll
            for (int kk = 0; kk < 4; kk++)
                af[m][kk] = *reinterpret_cast<const i64*>(rp + ((kk * 32 + g * 8) ^ x));
        }
#pragma unroll
        for (int nf = 0; nf < 4; nf++) {
            int row = dg * 64 + nf * 16 + l15;
            const char* rp = (const char*)Bs + row * 128;
            int x = (row & 7) << 4;
#pragma unroll
            for (int kk = 0; kk < 4; kk++)
                bv[nf][kk] = *reinterpret_cast<const i64*>(rp + ((kk * 32 + g * 8) ^ x));
        }
        __syncthreads();                       // all reads done: LDS free
        if (t + 1 < LK / 128) stage(t + 1);    // next tile flies under 64 MFMAs
#pragma unroll
        for (int kk = 0; kk < 4; kk++)
#pragma unroll
            for (int nf = 0; nf < 4; nf++)
#pragma unroll
                for (int m = 0; m < 4; m++)
                    acc[m][nf] = MFMAF8(af[m][kk], bv[nf][kk], acc[m][nf]);
    }
#pragma unroll
    for (int m = 0; m < 4; m++)
#pragma unroll
        for (int nf = 0; nf < 4; nf++)
#pragma unroll
            for (int j = 0; j < 4; j++) {
                int q = q0 + qg * 64 + m * 16 + g * 4 + j;
                int d = n0 + dg * 64 + nf * 16 + l15;
                size_t idx = ((size_t)q * BB + b) * DD + d;
                tout[idx] = f2bf(query[idx] - acc[m][nf][j] * ESCALE_INV);
            }
}

// out = relu( t @ Wtb^T ): 128x128 tile, bf16 staged, K=512
__global__ __launch_bounds__(256, 3) void k_final(const u16* __restrict__ t, const u16* __restrict__ Wtb,
                                                  float* __restrict__ out)
{
    const int r0 = blockIdx.x * 128, n0 = blockIdx.y * 128;
    const int tid = threadIdx.x, wv = tid >> 6, lane = tid & 63, l15 = lane & 15, g = lane >> 4;
    const int qg = wv >> 1, dg = wv & 1;

    __shared__ __align__(16) u16 As[128 * 64], Bs[128 * 64];

    const int srow = wv * 8 + (lane >> 3);
    const int scb = ((lane & 7) * 16) ^ ((srow & 7) << 4);
    const char* gA = (const char*)(t + (size_t)(r0 + srow) * DD) + scb;
    const char* gB = (const char*)(Wtb + (size_t)(n0 + srow) * DD) + scb;
    const size_t rstep = (size_t)32 * DD * 2;

    f32x4 z = {0.f, 0.f, 0.f, 0.f};
    f32x4 acc[4][4];
#pragma unroll
    for (int m = 0; m < 4; m++)
#pragma unroll
        for (int nf = 0; nf < 4; nf++) acc[m][nf] = z;

#pragma unroll
    for (int p = 0; p < 4; ++p) {
        gload16(gA + p * rstep, (char*)As + p * 4096 + wv * 1024);
        gload16(gB + p * rstep, (char*)Bs + p * 4096 + wv * 1024);
    }

    for (int tt = 0; tt < DD / 64; ++tt) {
        __syncthreads();
        bf16x8 af[4][2], bv[4][2];
#pragma unroll
        for (int m = 0; m < 4; m++) {
            int row = qg * 64 + m * 16 + l15;
            const char* rp = (const char*)As + row * 128;
            int x = (row & 7) << 4;
#pragma unroll
            for (int kk = 0; kk < 2; kk++)
                af[m][kk] = *reinterpret_cast<const bf16x8*>(rp + ((kk * 64 + g * 16) ^ x));
        }
#pragma unroll
        for (int nf = 0; nf < 4; nf++) {
            int row = dg * 64 + nf * 16 + l15;
            const char* rp = (const char*)Bs + row * 128;
            int x = (row & 7) << 4;
#pragma unroll
            for (int kk = 0; kk < 2; kk++)
                bv[nf][kk] = *reinterpret_cast<const bf16x8*>(rp + ((kk * 64 + g * 16) ^ x));
        }
        __syncthreads();
        if (tt + 1 < DD / 64) {
            int ktb = (tt + 1) * 128;
#pragma unroll
            for (int p = 0; p < 4; ++p) {
                gload16(gA + p * rstep + ktb, (char*)As + p * 4096 + wv * 1024);
                gload16(gB + p * rstep + ktb, (char*)Bs + p * 4096 + wv * 1024);
            }
        }
#pragma unroll
        for (int nf = 0; nf < 4; nf++)
#pragma unroll
            for (int m = 0; m < 4; m++) {
                acc[m][nf] = MFMA16(af[m][0], bv[nf][0], acc[m][nf]);
                acc[m][nf] = MFMA16(af[m][1], bv[nf][1], acc[m][nf]);
            }
    }
#pragma unroll
    for (int m = 0; m < 4; m++)
#pragma unroll
        for (int nf = 0; nf < 4; nf++)
#pragma unroll
            for (int j = 0; j < 4; j++)
                out[(size_t)(r0 + qg * 64 + m * 16 + g * 4 + j) * DD + n0 + dg * 64 + nf * 16 + l15] =
                    fmaxf(acc[m][nf][j], 0.f);
}

extern "C" void kernel_launch(void* const* d_in, const int* in_sizes, int n_in,
                              void* d_out, int out_size, void* d_ws, size_t ws_size,
                              hipStream_t stream)
{
    const float* query = (const float*)d_in[0];
    const float* key   = (const float*)d_in[1];
    const float* value = (const float*)d_in[2];
    const float* WK    = (const float*)d_in[3];
    const float* WQ    = (const float*)d_in[4];
    const float* WV    = (const float*)d_in[5];
    const float* Wt    = (const float*)d_in[6];
    float* out = (float*)d_out;

    char* ws = (char*)d_ws;
    u16*   wqb = (u16*)(ws);                                   //  4 MB [B][LQ][64] bf16
    u16*   wkb = (u16*)(ws + (4u << 20));                      //  4 MB [B][LK][64] bf16
    u8*    wvS = (u8*)(ws + (8u << 20));                       // 16 MB [B][512][LK] fp8
    u16*   t   = (u16*)(ws + (24u << 20));                     // 32 MB [LQ][B][512] bf16
    float* Rq  = (float*)(ws + (56u << 20));                   // 128 KB [B][LQ] f32
    float* ci  = (float*)(ws + (56u << 20) + (128u << 10));    // 128 KB [B][LK] f32
    u16*   WQb = (u16*)(ws + (56u << 20) + (256u << 10));      // 64 KB
    u16*   WKb = (u16*)(ws + (56u << 20) + (320u << 10));      // 64 KB
    u16*   WVb = (u16*)(ws + (56u << 20) + (384u << 10));      // 512 KB
    u16*   Wtb = (u16*)(ws + (56u << 20) + (896u << 10));      // 512 KB
    u8*    E   = (u8*)(ws + (58ull << 20));                    // 4 MB * G (fp8)

    int G = 0;
    const size_t fixed = 58ull << 20;
    for (int g = 16; g >= 1; g >>= 1)
        if (fixed + ((size_t)g << 22) <= ws_size) { G = g; break; }
    if (G == 0) G = 1;

    k_cvt<<<32, 256, 0, stream>>>(WQ, WQb, DKK * DD);
    k_cvt<<<32, 256, 0, stream>>>(WK, WKb, DKK * DD);
    k_cvt<<<256, 256, 0, stream>>>(WV, WVb, DD * DD);
    k_cvt<<<256, 256, 0, stream>>>(Wt, Wtb, DD * DD);

    k_projqk<<<dim3(LQ / 64, BB, 2), 256, 0, stream>>>(query, key, WQb, WKb, wqb, wkb);

    // pass 1: Rq[b][q] = 1/sum_k exp(s)
    k_expsum<<<dim3(LQ / 128, BB), 256, 0, stream>>>(wqb, wkb, nullptr, Rq, 0.f, nullptr, 0);

    for (int b0 = 0; b0 < BB; b0 += G) {
        // pass 2: ci[b][k] = 1/(eps+sum_q exp*Rq), E[q][k] = fp8(exp*Rq*1024)
        k_expsum<<<dim3(LK / 128, G), 256, 0, stream>>>(wkb, wqb, Rq, ci, EPSF, E, b0);
        // wvS = fp8((value@WV^T)*ci)
        k_projv<<<dim3(LK / 128, DD / 128, G), 256, 0, stream>>>(value, WVb, ci, wvS, b0);
        // t = query - (E @ wvS^T)/1024
        k_pvgemm<<<64 * G, 256, 0, stream>>>(query, E, wvS, t, b0, G);
    }

    k_final<<<dim3(LQ * BB / 128, DD / 128), 256, 0, stream>>>(t, Wtb, out);
}

// Round 8
// 335.227 us; speedup vs baseline: 1.9712x; 1.0466x over previous
//
#include <hip/hip_runtime.h>

#define LQ 2048
#define LK 2048
#define BB 16
#define DD 512
#define DKK 64
#define EPSF 1e-9f

typedef unsigned short u16;
typedef unsigned char u8;
typedef long i64;
typedef __attribute__((ext_vector_type(8))) short bf16x8;
typedef __attribute__((ext_vector_type(4))) float f32x4;
#define MFMA16(a, b, c) __builtin_amdgcn_mfma_f32_16x16x32_bf16(a, b, c, 0, 0, 0)
#define MFMAF8(a, b, c) __builtin_amdgcn_mfma_f32_16x16x32_fp8_fp8(a, b, c, 0, 0, 0)
#define ESCALE 1024.0f
#define ESCALE_INV 0.0009765625f

__device__ inline u16 f2bf(float f) {
    unsigned int u = __float_as_uint(f);
    u += 0x7fffu + ((u >> 16) & 1u);   // RNE
    return (u16)(u >> 16);
}
__device__ inline bf16x8 cvt8(float4 a, float4 b) {
    bf16x8 r;
    r[0] = (short)f2bf(a.x); r[1] = (short)f2bf(a.y); r[2] = (short)f2bf(a.z); r[3] = (short)f2bf(a.w);
    r[4] = (short)f2bf(b.x); r[5] = (short)f2bf(b.y); r[6] = (short)f2bf(b.z); r[7] = (short)f2bf(b.w);
    return r;
}
__device__ inline int pk_fp8x4(float a, float b, float c, float d) {
    int r = __builtin_amdgcn_cvt_pk_fp8_f32(a, b, 0, false);
    r = __builtin_amdgcn_cvt_pk_fp8_f32(c, d, r, true);
    return r;
}
__device__ inline void gload16(const void* g, void* l) {
    __builtin_amdgcn_global_load_lds((const __attribute__((address_space(1))) unsigned int*)g,
                                     (__attribute__((address_space(3))) unsigned int*)l, 16, 0, 0);
}

__global__ __launch_bounds__(256) void k_cvt(const float* __restrict__ src, u16* __restrict__ dst, int n) {
    int i = (blockIdx.x * 256 + threadIdx.x) * 4;
    if (i < n) {
        float4 v = *reinterpret_cast<const float4*>(src + i);
        *reinterpret_cast<ushort4*>(dst + i) = make_ushort4(f2bf(v.x), f2bf(v.y), f2bf(v.z), f2bf(v.w));
    }
}

// value f32 [LK][B][D] -> vb bf16 [B][LK][D]; each wave handles one contiguous src row chunk
__global__ __launch_bounds__(256) void k_cvtv(const float* __restrict__ value, u16* __restrict__ vb) {
    size_t i = ((size_t)blockIdx.x * 256 + threadIdx.x) * 8;
    int k = (int)(i >> 13);            // / (B*D) = 8192
    int r = (int)(i & 8191);
    int b = r >> 9, d = r & 511;
    float4 a = *reinterpret_cast<const float4*>(value + i);
    float4 c = *reinterpret_cast<const float4*>(value + i + 4);
    *reinterpret_cast<bf16x8*>(vb + ((size_t)b * LK + k) * DD + d) = cvt8(a, c);
}

// fused q/k projection + l2norm.  z=0: query->wq, z=1: key->wk.  BM=64 (wave owns 16 rows)
__global__ __launch_bounds__(256) void k_projqk(const float* __restrict__ xq, const float* __restrict__ xk,
                                                const u16* __restrict__ Wq, const u16* __restrict__ Wk,
                                                u16* __restrict__ yq, u16* __restrict__ yk)
{
    const float* x = blockIdx.z ? xk : xq;
    const u16* Wb = blockIdx.z ? Wk : Wq;
    u16* y = blockIdx.z ? yk : yq;
    const int b = blockIdx.y, r0 = blockIdx.x * 64;
    const int tid = threadIdx.x, wave = tid >> 6, lane = tid & 63, l15 = lane & 15, g = lane >> 4;
    const int rw = r0 + wave * 16;
    f32x4 z = {0.f, 0.f, 0.f, 0.f};
    f32x4 acc[4];
#pragma unroll
    for (int nf = 0; nf < 4; nf++) acc[nf] = z;

    for (int kt = 0; kt < DD; kt += 32) {
        const float* p = x + ((size_t)(rw + l15) * BB + b) * DD + kt + g * 8;
        bf16x8 af = cvt8(*reinterpret_cast<const float4*>(p), *reinterpret_cast<const float4*>(p + 4));
#pragma unroll
        for (int nf = 0; nf < 4; nf++) {
            bf16x8 bf_ = *reinterpret_cast<const bf16x8*>(Wb + (size_t)(nf * 16 + l15) * DD + kt + g * 8);
            acc[nf] = MFMA16(af, bf_, acc[nf]);
        }
    }
    float rn[4];
#pragma unroll
    for (int j = 0; j < 4; j++) {
        float t2 = acc[0][j] * acc[0][j] + acc[1][j] * acc[1][j]
                 + acc[2][j] * acc[2][j] + acc[3][j] * acc[3][j];
        t2 += __shfl_xor(t2, 1, 64);
        t2 += __shfl_xor(t2, 2, 64);
        t2 += __shfl_xor(t2, 4, 64);
        t2 += __shfl_xor(t2, 8, 64);
        rn[j] = 1.f / fmaxf(sqrtf(t2), 1e-12f);
    }
#pragma unroll
    for (int nf = 0; nf < 4; nf++)
#pragma unroll
        for (int j = 0; j < 4; j++) {
            int q = rw + g * 4 + j;
            y[((size_t)b * LQ + q) * DKK + nf * 16 + l15] = f2bf(acc[nf][j] * rn[j]);
        }
}

// wvS[b][d][k] = fp8( (vb[b][k,:] @ WVb[d,:]) * ci[b][k] )  -- staged GEMM (k_final clone)
__global__ __launch_bounds__(256, 3) void k_projv(const u16* __restrict__ vb, const u16* __restrict__ WVb,
                                                  const float* __restrict__ ci, u8* __restrict__ wvS, int b0)
{
    const int b = b0 + blockIdx.z, k0 = blockIdx.x * 128, n0 = blockIdx.y * 128;
    const int tid = threadIdx.x, wv = tid >> 6, lane = tid & 63, l15 = lane & 15, g = lane >> 4;
    const int qg = wv >> 1, dg = wv & 1;

    __shared__ __align__(16) u16 As[128 * 64], Bs[128 * 64];

    const int srow = wv * 8 + (lane >> 3);
    const int scb = ((lane & 7) * 16) ^ ((srow & 7) << 4);
    const char* gA = (const char*)(vb + ((size_t)b * LK + k0 + srow) * DD) + scb;
    const char* gB = (const char*)(WVb + (size_t)(n0 + srow) * DD) + scb;
    const size_t rstep = (size_t)32 * DD * 2;

    f32x4 z = {0.f, 0.f, 0.f, 0.f};
    f32x4 acc[4][4];
#pragma unroll
    for (int m = 0; m < 4; m++)
#pragma unroll
        for (int nf = 0; nf < 4; nf++) acc[m][nf] = z;

#pragma unroll
    for (int p = 0; p < 4; ++p) {
        gload16(gA + p * rstep, (char*)As + p * 4096 + wv * 1024);
        gload16(gB + p * rstep, (char*)Bs + p * 4096 + wv * 1024);
    }

    for (int tt = 0; tt < DD / 64; ++tt) {
        __syncthreads();
        bf16x8 af[4][2], bv[4][2];
#pragma unroll
        for (int m = 0; m < 4; m++) {
            int row = qg * 64 + m * 16 + l15;
            const char* rp = (const char*)As + row * 128;
            int x = (row & 7) << 4;
#pragma unroll
            for (int kk = 0; kk < 2; kk++)
                af[m][kk] = *reinterpret_cast<const bf16x8*>(rp + ((kk * 64 + g * 16) ^ x));
        }
#pragma unroll
        for (int nf = 0; nf < 4; nf++) {
            int row = dg * 64 + nf * 16 + l15;
            const char* rp = (const char*)Bs + row * 128;
            int x = (row & 7) << 4;
#pragma unroll
            for (int kk = 0; kk < 2; kk++)
                bv[nf][kk] = *reinterpret_cast<const bf16x8*>(rp + ((kk * 64 + g * 16) ^ x));
        }
        __syncthreads();
        if (tt + 1 < DD / 64) {
            int ktb = (tt + 1) * 128;
#pragma unroll
            for (int p = 0; p < 4; ++p) {
                gload16(gA + p * rstep + ktb, (char*)As + p * 4096 + wv * 1024);
                gload16(gB + p * rstep + ktb, (char*)Bs + p * 4096 + wv * 1024);
            }
        }
#pragma unroll
        for (int nf = 0; nf < 4; nf++)
#pragma unroll
            for (int m = 0; m < 4; m++) {
                acc[m][nf] = MFMA16(af[m][0], bv[nf][0], acc[m][nf]);
                acc[m][nf] = MFMA16(af[m][1], bv[nf][1], acc[m][nf]);
            }
    }
#pragma unroll
    for (int m = 0; m < 4; m++) {
        float cv[4];
        int kb = k0 + qg * 64 + m * 16 + g * 4;
#pragma unroll
        for (int j = 0; j < 4; j++) cv[j] = ci[(size_t)b * LK + kb + j];
#pragma unroll
        for (int nf = 0; nf < 4; nf++) {
            int d = n0 + dg * 64 + nf * 16 + l15;
            *reinterpret_cast<int*>(wvS + ((size_t)b * DD + d) * LK + kb) =
                pk_fp8x4(acc[m][nf][0] * cv[0], acc[m][nf][1] * cv[1],
                         acc[m][nf][2] * cv[2], acc[m][nf][3] * cv[3]);
        }
    }
}

// outv[row] = 1/(eps + sum_cols exp(s)*w[col]);  optionally E[col][row] = fp8(exp(s)*w[col]*1024)
// 64 rows/block (grid 2x -> 2 blocks/CU)
__global__ __launch_bounds__(256) void k_expsum(const u16* __restrict__ A, const u16* __restrict__ Bm,
                                                const float* __restrict__ wcol, float* __restrict__ outv,
                                                float eps, u8* __restrict__ E, int b0)
{
    const int b = b0 + blockIdx.y, r0 = blockIdx.x * 64;
    const int tid = threadIdx.x, wave = tid >> 6, lane = tid & 63, l15 = lane & 15, g = lane >> 4;
    f32x4 z = {0.f, 0.f, 0.f, 0.f};
    u8* Eb = E ? (E + (size_t)blockIdx.y * LQ * LK) : nullptr;

    const u16* ar = A + ((size_t)b * LK + r0 + wave * 16 + l15) * DKK;
    bf16x8 af0 = *reinterpret_cast<const bf16x8*>(ar + g * 8);
    bf16x8 af1 = *reinterpret_cast<const bf16x8*>(ar + 32 + g * 8);
    float acc[4] = {0.f, 0.f, 0.f, 0.f};

    for (int ct = 0; ct < LK; ct += 64) {
#pragma unroll
        for (int n = 0; n < 4; n++) {
            int col = ct + n * 16;
            const u16* br = Bm + ((size_t)b * LK + col + l15) * DKK;
            bf16x8 b0v = *reinterpret_cast<const bf16x8*>(br + g * 8);
            bf16x8 b1v = *reinterpret_cast<const bf16x8*>(br + 32 + g * 8);
            float w = wcol ? wcol[(size_t)b * LK + col + l15] : 1.f;
            f32x4 s = z;
            s = MFMA16(af0, b0v, s);
            s = MFMA16(af1, b1v, s);
            float pe[4];
#pragma unroll
            for (int j = 0; j < 4; j++) { pe[j] = __expf(s[j]) * w; acc[j] += pe[j]; }
            if (Eb) {
                size_t idx = (size_t)(col + l15) * LK + r0 + wave * 16 + g * 4;
                *reinterpret_cast<int*>(Eb + idx) =
                    pk_fp8x4(pe[0] * ESCALE, pe[1] * ESCALE, pe[2] * ESCALE, pe[3] * ESCALE);
            }
        }
    }
#pragma unroll
    for (int j = 0; j < 4; j++) {
        float v = acc[j];
        v += __shfl_xor(v, 1, 64);
        v += __shfl_xor(v, 2, 64);
        v += __shfl_xor(v, 4, 64);
        v += __shfl_xor(v, 8, 64);
        if (l15 == 0) outv[(size_t)b * LK + r0 + wave * 16 + g * 4 + j] = 1.f / (eps + v);
    }
}

// t[q,b,:] = query - (E @ wvS^T)/1024.  fp8 GEMM: 128x128 tile, BK=128, LDS-staged
__global__ __launch_bounds__(256, 3) void k_pvgemm(const float* __restrict__ query,
                                                   const u8* __restrict__ E,
                                                   const u8* __restrict__ wvS,
                                                   u16* __restrict__ tout, int b0, int G)
{
    const int i = blockIdx.x;
    int bl, tile;
    if (G == 16) { bl = (i & 7) + 8 * (i >> 9); tile = (i >> 3) & 63; }
    else         { bl = i % G; tile = i / G; }
    const int b = b0 + bl;
    const int q0 = (tile >> 2) * 128, n0 = (tile & 3) * 128;
    const int tid = threadIdx.x, wv = tid >> 6, lane = tid & 63, l15 = lane & 15, g = lane >> 4;
    const int qg = wv >> 1, dg = wv & 1;

    __shared__ __align__(16) char As[16384], Bs[16384];

    const u8* Eb = E + (size_t)bl * LQ * LK;
    const u8* Vb = wvS + (size_t)b * DD * LK;

    const int srow = wv * 8 + (lane >> 3);
    const int scb = ((lane & 7) * 16) ^ ((srow & 7) << 4);
    const char* gA = (const char*)Eb + (size_t)(q0 + srow) * LK + scb;
    const char* gB = (const char*)Vb + (size_t)(n0 + srow) * LK + scb;
    const size_t rstep = (size_t)32 * LK;

    f32x4 z = {0.f, 0.f, 0.f, 0.f};
    f32x4 acc[4][4];
#pragma unroll
    for (int m = 0; m < 4; m++)
#pragma unroll
        for (int nf = 0; nf < 4; nf++) acc[m][nf] = z;

    auto stage = [&](int t) {
#pragma unroll
        for (int p = 0; p < 4; ++p) {
            gload16(gA + p * rstep + t * 128, (char*)As + p * 4096 + wv * 1024);
            gload16(gB + p * rstep + t * 128, (char*)Bs + p * 4096 + wv * 1024);
        }
    };
    stage(0);

    for (int t = 0; t < LK / 128; ++t) {
        __syncthreads();
        i64 af[4][4], bv[4][4];
#pragma unroll
        for (int m = 0; m < 4; m++) {
            int row = qg * 64 + m * 16 + l15;
            const char* rp = (const char*)As + row * 128;
            int x = (row & 7) << 4;
#pragma unroll
            for (int kk = 0; kk < 4; kk++)
                af[m][kk] = *reinterpret_cast<const i64*>(rp + ((kk * 32 + g * 8) ^ x));
        }
#pragma unroll
        for (int nf = 0; nf < 4; nf++) {
            int row = dg * 64 + nf * 16 + l15;
            const char* rp = (const char*)Bs + row * 128;
            int x = (row & 7) << 4;
#pragma unroll
            for (int kk = 0; kk < 4; kk++)
                bv[nf][kk] = *reinterpret_cast<const i64*>(rp + ((kk * 32 + g * 8) ^ x));
        }
        __syncthreads();
        if (t + 1 < LK / 128) stage(t + 1);
#pragma unroll
        for (int kk = 0; kk < 4; kk++)
#pragma unroll
            for (int nf = 0; nf < 4; nf++)
#pragma unroll
                for (int m = 0; m < 4; m++)
                    acc[m][nf] = MFMAF8(af[m][kk], bv[nf][kk], acc[m][nf]);
    }
#pragma unroll
    for (int m = 0; m < 4; m++)
#pragma unroll
        for (int nf = 0; nf < 4; nf++)
#pragma unroll
            for (int j = 0; j < 4; j++) {
                int q = q0 + qg * 64 + m * 16 + g * 4 + j;
                int d = n0 + dg * 64 + nf * 16 + l15;
                size_t idx = ((size_t)q * BB + b) * DD + d;
                tout[idx] = f2bf(query[idx] - acc[m][nf][j] * ESCALE_INV);
            }
}

// out = relu( t @ Wtb^T ): 128x128 tile, bf16 staged, K=512
__global__ __launch_bounds__(256, 3) void k_final(const u16* __restrict__ t, const u16* __restrict__ Wtb,
                                                  float* __restrict__ out)
{
    const int r0 = blockIdx.x * 128, n0 = blockIdx.y * 128;
    const int tid = threadIdx.x, wv = tid >> 6, lane = tid & 63, l15 = lane & 15, g = lane >> 4;
    const int qg = wv >> 1, dg = wv & 1;

    __shared__ __align__(16) u16 As[128 * 64], Bs[128 * 64];

    const int srow = wv * 8 + (lane >> 3);
    const int scb = ((lane & 7) * 16) ^ ((srow & 7) << 4);
    const char* gA = (const char*)(t + (size_t)(r0 + srow) * DD) + scb;
    const char* gB = (const char*)(Wtb + (size_t)(n0 + srow) * DD) + scb;
    const size_t rstep = (size_t)32 * DD * 2;

    f32x4 z = {0.f, 0.f, 0.f, 0.f};
    f32x4 acc[4][4];
#pragma unroll
    for (int m = 0; m < 4; m++)
#pragma unroll
        for (int nf = 0; nf < 4; nf++) acc[m][nf] = z;

#pragma unroll
    for (int p = 0; p < 4; ++p) {
        gload16(gA + p * rstep, (char*)As + p * 4096 + wv * 1024);
        gload16(gB + p * rstep, (char*)Bs + p * 4096 + wv * 1024);
    }

    for (int tt = 0; tt < DD / 64; ++tt) {
        __syncthreads();
        bf16x8 af[4][2], bv[4][2];
#pragma unroll
        for (int m = 0; m < 4; m++) {
            int row = qg * 64 + m * 16 + l15;
            const char* rp = (const char*)As + row * 128;
            int x = (row & 7) << 4;
#pragma unroll
            for (int kk = 0; kk < 2; kk++)
                af[m][kk] = *reinterpret_cast<const bf16x8*>(rp + ((kk * 64 + g * 16) ^ x));
        }
#pragma unroll
        for (int nf = 0; nf < 4; nf++) {
            int row = dg * 64 + nf * 16 + l15;
            const char* rp = (const char*)Bs + row * 128;
            int x = (row & 7) << 4;
#pragma unroll
            for (int kk = 0; kk < 2; kk++)
                bv[nf][kk] = *reinterpret_cast<const bf16x8*>(rp + ((kk * 64 + g * 16) ^ x));
        }
        __syncthreads();
        if (tt + 1 < DD / 64) {
            int ktb = (tt + 1) * 128;
#pragma unroll
            for (int p = 0; p < 4; ++p) {
                gload16(gA + p * rstep + ktb, (char*)As + p * 4096 + wv * 1024);
                gload16(gB + p * rstep + ktb, (char*)Bs + p * 4096 + wv * 1024);
            }
        }
#pragma unroll
        for (int nf = 0; nf < 4; nf++)
#pragma unroll
            for (int m = 0; m < 4; m++) {
                acc[m][nf] = MFMA16(af[m][0], bv[nf][0], acc[m][nf]);
                acc[m][nf] = MFMA16(af[m][1], bv[nf][1], acc[m][nf]);
            }
    }
#pragma unroll
    for (int m = 0; m < 4; m++)
#pragma unroll
        for (int nf = 0; nf < 4; nf++)
#pragma unroll
            for (int j = 0; j < 4; j++)
                out[(size_t)(r0 + qg * 64 + m * 16 + g * 4 + j) * DD + n0 + dg * 64 + nf * 16 + l15] =
                    fmaxf(acc[m][nf][j], 0.f);
}

extern "C" void kernel_launch(void* const* d_in, const int* in_sizes, int n_in,
                              void* d_out, int out_size, void* d_ws, size_t ws_size,
                              hipStream_t stream)
{
    const float* query = (const float*)d_in[0];
    const float* key   = (const float*)d_in[1];
    const float* value = (const float*)d_in[2];
    const float* WK    = (const float*)d_in[3];
    const float* WQ    = (const float*)d_in[4];
    const float* WV    = (const float*)d_in[5];
    const float* Wt    = (const float*)d_in[6];
    float* out = (float*)d_out;

    char* ws = (char*)d_ws;
    u16*   wqb = (u16*)(ws);                                   //  4 MB [B][LQ][64] bf16
    u16*   wkb = (u16*)(ws + (4u << 20));                      //  4 MB [B][LK][64] bf16
    u8*    wvS = (u8*)(ws + (8u << 20));                       // 16 MB [B][512][LK] fp8
    u16*   t   = (u16*)(ws + (24u << 20));                     // 32 MB [LQ][B][512] bf16
    u16*   vb  = (u16*)(ws + (56u << 20));                     // 32 MB [B][LK][512] bf16
    float* Rq  = (float*)(ws + (88u << 20));                   // 128 KB [B][LQ] f32
    float* ci  = (float*)(ws + (88u << 20) + (128u << 10));    // 128 KB [B][LK] f32
    u16*   WQb = (u16*)(ws + (88u << 20) + (256u << 10));      // 64 KB
    u16*   WKb = (u16*)(ws + (88u << 20) + (320u << 10));      // 64 KB
    u16*   WVb = (u16*)(ws + (88u << 20) + (384u << 10));      // 512 KB
    u16*   Wtb = (u16*)(ws + (88u << 20) + (896u << 10));      // 512 KB
    u8*    E   = (u8*)(ws + (90ull << 20));                    // 4 MB * G (fp8)

    int G = 0;
    const size_t fixed = 90ull << 20;
    for (int g = 16; g >= 1; g >>= 1)
        if (fixed + ((size_t)g << 22) <= ws_size) { G = g; break; }
    if (G == 0) G = 1;

    k_cvt<<<32, 256, 0, stream>>>(WQ, WQb, DKK * DD);
    k_cvt<<<32, 256, 0, stream>>>(WK, WKb, DKK * DD);
    k_cvt<<<256, 256, 0, stream>>>(WV, WVb, DD * DD);
    k_cvt<<<256, 256, 0, stream>>>(Wt, Wtb, DD * DD);
    k_cvtv<<<8192, 256, 0, stream>>>(value, vb);

    k_projqk<<<dim3(LQ / 64, BB, 2), 256, 0, stream>>>(query, key, WQb, WKb, wqb, wkb);

    // pass 1: Rq[b][q] = 1/sum_k exp(s)
    k_expsum<<<dim3(LQ / 64, BB), 256, 0, stream>>>(wqb, wkb, nullptr, Rq, 0.f, nullptr, 0);

    for (int b0 = 0; b0 < BB; b0 += G) {
        // pass 2: ci[b][k] = 1/(eps+sum_q exp*Rq), E[q][k] = fp8(exp*Rq*1024)
        k_expsum<<<dim3(LK / 64, G), 256, 0, stream>>>(wkb, wqb, Rq, ci, EPSF, E, b0);
        // wvS = fp8((vb@WV^T)*ci)
        k_projv<<<dim3(LK / 128, DD / 128, G), 256, 0, stream>>>(vb, WVb, ci, wvS, b0);
        // t = query - (E @ wvS^T)/1024
        k_pvgemm<<<64 * G, 256, 0, stream>>>(query, E, wvS, t, b0, G);
    }

    k_final<<<dim3(LQ * BB / 128, DD / 128), 256, 0, stream>>>(t, Wtb, out);
}

// Round 9
// 303.589 us; speedup vs baseline: 2.1766x; 1.1042x over previous
//
#include <hip/hip_runtime.h>

#define LQ 2048
#define LK 2048
#define BB 16
#define DD 512
#define DKK 64
#define EPSF 1e-9f

typedef unsigned short u16;
typedef unsigned char u8;
typedef long i64;
typedef __attribute__((ext_vector_type(8))) short bf16x8;
typedef __attribute__((ext_vector_type(4))) float f32x4;
#define MFMA16(a, b, c) __builtin_amdgcn_mfma_f32_16x16x32_bf16(a, b, c, 0, 0, 0)
#define MFMAF8(a, b, c) __builtin_amdgcn_mfma_f32_16x16x32_fp8_fp8(a, b, c, 0, 0, 0)

__device__ inline u16 f2bf(float f) {
    unsigned int u = __float_as_uint(f);
    u += 0x7fffu + ((u >> 16) & 1u);   // RNE
    return (u16)(u >> 16);
}
__device__ inline bf16x8 cvt8(float4 a, float4 b) {
    bf16x8 r;
    r[0] = (short)f2bf(a.x); r[1] = (short)f2bf(a.y); r[2] = (short)f2bf(a.z); r[3] = (short)f2bf(a.w);
    r[4] = (short)f2bf(b.x); r[5] = (short)f2bf(b.y); r[6] = (short)f2bf(b.z); r[7] = (short)f2bf(b.w);
    return r;
}
__device__ inline int pk_fp8x4(float a, float b, float c, float d) {
    int r = __builtin_amdgcn_cvt_pk_fp8_f32(a, b, 0, false);
    r = __builtin_amdgcn_cvt_pk_fp8_f32(c, d, r, true);
    return r;
}
__device__ inline void gload16(const void* g, void* l) {
    __builtin_amdgcn_global_load_lds((const __attribute__((address_space(1))) unsigned int*)g,
                                     (__attribute__((address_space(3))) unsigned int*)l, 16, 0, 0);
}

__global__ __launch_bounds__(256) void k_cvt(const float* __restrict__ src, u16* __restrict__ dst, int n) {
    int i = (blockIdx.x * 256 + threadIdx.x) * 4;
    if (i < n) {
        float4 v = *reinterpret_cast<const float4*>(src + i);
        *reinterpret_cast<ushort4*>(dst + i) = make_ushort4(f2bf(v.x), f2bf(v.y), f2bf(v.z), f2bf(v.w));
    }
}

// value f32 [LK][B][D] -> vb bf16 [B][LK][D]
__global__ __launch_bounds__(256) void k_cvtv(const float* __restrict__ value, u16* __restrict__ vb) {
    size_t i = ((size_t)blockIdx.x * 256 + threadIdx.x) * 8;
    int k = (int)(i >> 13);
    int r = (int)(i & 8191);
    int b = r >> 9, d = r & 511;
    float4 a = *reinterpret_cast<const float4*>(value + i);
    float4 c = *reinterpret_cast<const float4*>(value + i + 4);
    *reinterpret_cast<bf16x8*>(vb + ((size_t)b * LK + k) * DD + d) = cvt8(a, c);
}

// fused q/k projection + l2norm
__global__ __launch_bounds__(256) void k_projqk(const float* __restrict__ xq, const float* __restrict__ xk,
                                                const u16* __restrict__ Wq, const u16* __restrict__ Wk,
                                                u16* __restrict__ yq, u16* __restrict__ yk)
{
    const float* x = blockIdx.z ? xk : xq;
    const u16* Wb = blockIdx.z ? Wk : Wq;
    u16* y = blockIdx.z ? yk : yq;
    const int b = blockIdx.y, r0 = blockIdx.x * 64;
    const int tid = threadIdx.x, wave = tid >> 6, lane = tid & 63, l15 = lane & 15, g = lane >> 4;
    const int rw = r0 + wave * 16;
    f32x4 z = {0.f, 0.f, 0.f, 0.f};
    f32x4 acc[4];
#pragma unroll
    for (int nf = 0; nf < 4; nf++) acc[nf] = z;

    for (int kt = 0; kt < DD; kt += 32) {
        const float* p = x + ((size_t)(rw + l15) * BB + b) * DD + kt + g * 8;
        bf16x8 af = cvt8(*reinterpret_cast<const float4*>(p), *reinterpret_cast<const float4*>(p + 4));
#pragma unroll
        for (int nf = 0; nf < 4; nf++) {
            bf16x8 bf_ = *reinterpret_cast<const bf16x8*>(Wb + (size_t)(nf * 16 + l15) * DD + kt + g * 8);
            acc[nf] = MFMA16(af, bf_, acc[nf]);
        }
    }
    float rn[4];
#pragma unroll
    for (int j = 0; j < 4; j++) {
        float t2 = acc[0][j] * acc[0][j] + acc[1][j] * acc[1][j]
                 + acc[2][j] * acc[2][j] + acc[3][j] * acc[3][j];
        t2 += __shfl_xor(t2, 1, 64);
        t2 += __shfl_xor(t2, 2, 64);
        t2 += __shfl_xor(t2, 4, 64);
        t2 += __shfl_xor(t2, 8, 64);
        rn[j] = 1.f / fmaxf(sqrtf(t2), 1e-12f);
    }
#pragma unroll
    for (int nf = 0; nf < 4; nf++)
#pragma unroll
        for (int j = 0; j < 4; j++) {
            int q = rw + g * 4 + j;
            y[((size_t)b * LQ + q) * DKK + nf * 16 + l15] = f2bf(acc[nf][j] * rn[j]);
        }
}

// Single QK^T pass: E0[bl][q][k] = fp8(exp(s_qk)); Rpart[bl][p][q] = partial row sums.
// grid (LK/64, LQ/512, G)
__global__ __launch_bounds__(256) void k_score(const u16* __restrict__ wqb, const u16* __restrict__ wkb,
                                               u8* __restrict__ E0, float* __restrict__ Rpart, int b0)
{
    const int kb = blockIdx.x, c = blockIdx.y, bl = blockIdx.z, b = b0 + bl;
    const int tid = threadIdx.x, wave = tid >> 6, lane = tid & 63, l15 = lane & 15, g = lane >> 4;
    const int k0 = kb * 64;
    f32x4 z = {0.f, 0.f, 0.f, 0.f};

    const u16* ar = wkb + ((size_t)b * LK + k0 + wave * 16 + l15) * DKK;
    bf16x8 af0 = *reinterpret_cast<const bf16x8*>(ar + g * 8);
    bf16x8 af1 = *reinterpret_cast<const bf16x8*>(ar + 32 + g * 8);
    u8* Eb = E0 + (size_t)bl * LQ * LK;
    float* Rp = Rpart + ((size_t)bl * 128 + kb * 4 + wave) * LQ;

    for (int ct = 0; ct < 512; ct += 64) {
#pragma unroll
        for (int n = 0; n < 4; n++) {
            int q = c * 512 + ct + n * 16 + l15;
            const u16* br = wqb + ((size_t)b * LQ + q) * DKK;
            bf16x8 b0v = *reinterpret_cast<const bf16x8*>(br + g * 8);
            bf16x8 b1v = *reinterpret_cast<const bf16x8*>(br + 32 + g * 8);
            f32x4 s = z;
            s = MFMA16(af0, b0v, s);
            s = MFMA16(af1, b1v, s);
            float pe[4];
#pragma unroll
            for (int j = 0; j < 4; j++) pe[j] = __expf(s[j]);
            *reinterpret_cast<int*>(Eb + (size_t)q * LK + k0 + wave * 16 + g * 4) =
                pk_fp8x4(pe[0], pe[1], pe[2], pe[3]);
            float v = pe[0] + pe[1] + pe[2] + pe[3];
            v += __shfl_xor(v, 16, 64);
            v += __shfl_xor(v, 32, 64);
            if (g == 0) Rp[q] = v;
        }
    }
}

// Rq[b][q] = 1 / sum_p Rpart[bl][p][q]
__global__ __launch_bounds__(256) void k_rsum(const float* __restrict__ Rpart, float* __restrict__ Rq, int b0) {
    int idx = blockIdx.x * 256 + threadIdx.x;
    int bl = idx >> 11, q = idx & 2047;
    const float* rp = Rpart + (size_t)bl * 128 * LQ + q;
    float s = 0.f;
    for (int p = 0; p < 128; p++) s += rp[(size_t)p * LQ];
    Rq[(size_t)(b0 + bl) * LQ + q] = 1.f / s;
}

// Cpart[bl][qc][k] = sum over 128 q of E0[q][k]*Rq[q].  grid (2, 16, G)
__global__ __launch_bounds__(256) void k_colsum(const u8* __restrict__ E0, const float* __restrict__ Rq,
                                                float* __restrict__ Cpart, int b0)
{
    const int kc = blockIdx.x, qc = blockIdx.y, bl = blockIdx.z;
    const int tid = threadIdx.x, sub = tid >> 6, lane = tid & 63;
    const u8* Eb = E0 + (size_t)bl * LQ * LK + (size_t)kc * 1024 + lane * 16;
    const float* rq = Rq + (size_t)(b0 + bl) * LQ + qc * 128;
    float acc[16];
#pragma unroll
    for (int i = 0; i < 16; i++) acc[i] = 0.f;
    for (int qi = 0; qi < 32; qi++) {
        int q = qi * 4 + sub;
        uint4 raw = *reinterpret_cast<const uint4*>(Eb + (size_t)(qc * 128 + q) * LK);
        float w = rq[q];
        const unsigned int* rw = (const unsigned int*)&raw;
#pragma unroll
        for (int dw = 0; dw < 4; dw++) {
            unsigned int u = rw[dw];
#pragma unroll
            for (int by = 0; by < 4; by++) {
                // e4m3fn -> f32 for positive normals (E0 in [0.37, 2.72])
                unsigned int f = 0x3C000000u + (((u >> (8 * by)) & 0x7Fu) << 20);
                acc[dw * 4 + by] += __uint_as_float(f) * w;
            }
        }
    }
    __shared__ float red[4][64][16];
#pragma unroll
    for (int i = 0; i < 16; i++) red[sub][lane][i] = acc[i];
    __syncthreads();
    if (sub == 0) {
#pragma unroll
        for (int i = 0; i < 16; i++) {
            float v = red[0][lane][i] + red[1][lane][i] + red[2][lane][i] + red[3][lane][i];
            Cpart[((size_t)bl * 16 + qc) * LK + kc * 1024 + lane * 16 + i] = v;
        }
    }
}

// ci[b][k] = 1/(eps + sum_qc Cpart)
__global__ __launch_bounds__(256) void k_csum(const float* __restrict__ Cpart, float* __restrict__ ci, int b0) {
    int idx = blockIdx.x * 256 + threadIdx.x;
    int bl = idx >> 11, k = idx & 2047;
    const float* cp = Cpart + (size_t)bl * 16 * LK + k;
    float s = 0.f;
#pragma unroll
    for (int p = 0; p < 16; p++) s += cp[(size_t)p * LK];
    ci[(size_t)(b0 + bl) * LK + k] = 1.f / (EPSF + s);
}

// wvS[b][d][k] = fp8( (vb[b][k,:] @ WVb[d,:]) * ci[b][k] )  -- staged GEMM
__global__ __launch_bounds__(256, 3) void k_projv(const u16* __restrict__ vb, const u16* __restrict__ WVb,
                                                  const float* __restrict__ ci, u8* __restrict__ wvS, int b0)
{
    const int b = b0 + blockIdx.z, k0 = blockIdx.x * 128, n0 = blockIdx.y * 128;
    const int tid = threadIdx.x, wv = tid >> 6, lane = tid & 63, l15 = lane & 15, g = lane >> 4;
    const int qg = wv >> 1, dg = wv & 1;

    __shared__ __align__(16) u16 As[128 * 64], Bs[128 * 64];

    const int srow = wv * 8 + (lane >> 3);
    const int scb = ((lane & 7) * 16) ^ ((srow & 7) << 4);
    const char* gA = (const char*)(vb + ((size_t)b * LK + k0 + srow) * DD) + scb;
    const char* gB = (const char*)(WVb + (size_t)(n0 + srow) * DD) + scb;
    const size_t rstep = (size_t)32 * DD * 2;

    f32x4 z = {0.f, 0.f, 0.f, 0.f};
    f32x4 acc[4][4];
#pragma unroll
    for (int m = 0; m < 4; m++)
#pragma unroll
        for (int nf = 0; nf < 4; nf++) acc[m][nf] = z;

#pragma unroll
    for (int p = 0; p < 4; ++p) {
        gload16(gA + p * rstep, (char*)As + p * 4096 + wv * 1024);
        gload16(gB + p * rstep, (char*)Bs + p * 4096 + wv * 1024);
    }

    for (int tt = 0; tt < DD / 64; ++tt) {
        __syncthreads();
        bf16x8 af[4][2], bv[4][2];
#pragma unroll
        for (int m = 0; m < 4; m++) {
            int row = qg * 64 + m * 16 + l15;
            const char* rp = (const char*)As + row * 128;
            int x = (row & 7) << 4;
#pragma unroll
            for (int kk = 0; kk < 2; kk++)
                af[m][kk] = *reinterpret_cast<const bf16x8*>(rp + ((kk * 64 + g * 16) ^ x));
        }
#pragma unroll
        for (int nf = 0; nf < 4; nf++) {
            int row = dg * 64 + nf * 16 + l15;
            const char* rp = (const char*)Bs + row * 128;
            int x = (row & 7) << 4;
#pragma unroll
            for (int kk = 0; kk < 2; kk++)
                bv[nf][kk] = *reinterpret_cast<const bf16x8*>(rp + ((kk * 64 + g * 16) ^ x));
        }
        __syncthreads();
        if (tt + 1 < DD / 64) {
            int ktb = (tt + 1) * 128;
#pragma unroll
            for (int p = 0; p < 4; ++p) {
                gload16(gA + p * rstep + ktb, (char*)As + p * 4096 + wv * 1024);
                gload16(gB + p * rstep + ktb, (char*)Bs + p * 4096 + wv * 1024);
            }
        }
#pragma unroll
        for (int nf = 0; nf < 4; nf++)
#pragma unroll
            for (int m = 0; m < 4; m++) {
                acc[m][nf] = MFMA16(af[m][0], bv[nf][0], acc[m][nf]);
                acc[m][nf] = MFMA16(af[m][1], bv[nf][1], acc[m][nf]);
            }
    }
#pragma unroll
    for (int m = 0; m < 4; m++) {
        float cv[4];
        int kb = k0 + qg * 64 + m * 16 + g * 4;
#pragma unroll
        for (int j = 0; j < 4; j++) cv[j] = ci[(size_t)b * LK + kb + j];
#pragma unroll
        for (int nf = 0; nf < 4; nf++) {
            int d = n0 + dg * 64 + nf * 16 + l15;
            *reinterpret_cast<int*>(wvS + ((size_t)b * DD + d) * LK + kb) =
                pk_fp8x4(acc[m][nf][0] * cv[0], acc[m][nf][1] * cv[1],
                         acc[m][nf][2] * cv[2], acc[m][nf][3] * cv[3]);
        }
    }
}

// t[q,b,:] = query - Rq[q] * (E0 @ wvS^T).  fp8 GEMM, BK=128, LDS-staged
__global__ __launch_bounds__(256, 3) void k_pvgemm(const float* __restrict__ query,
                                                   const u8* __restrict__ E0,
                                                   const u8* __restrict__ wvS,
                                                   const float* __restrict__ Rq,
                                                   u16* __restrict__ tout, int b0, int G)
{
    const int i = blockIdx.x;
    int bl, tile;
    if (G == 16) { bl = (i & 7) + 8 * (i >> 9); tile = (i >> 3) & 63; }
    else         { bl = i % G; tile = i / G; }
    const int b = b0 + bl;
    const int q0 = (tile >> 2) * 128, n0 = (tile & 3) * 128;
    const int tid = threadIdx.x, wv = tid >> 6, lane = tid & 63, l15 = lane & 15, g = lane >> 4;
    const int qg = wv >> 1, dg = wv & 1;

    __shared__ __align__(16) char As[16384], Bs[16384];

    const u8* Eb = E0 + (size_t)bl * LQ * LK;
    const u8* Vb = wvS + (size_t)b * DD * LK;

    const int srow = wv * 8 + (lane >> 3);
    const int scb = ((lane & 7) * 16) ^ ((srow & 7) << 4);
    const char* gA = (const char*)Eb + (size_t)(q0 + srow) * LK + scb;
    const char* gB = (const char*)Vb + (size_t)(n0 + srow) * LK + scb;
    const size_t rstep = (size_t)32 * LK;

    f32x4 z = {0.f, 0.f, 0.f, 0.f};
    f32x4 acc[4][4];
#pragma unroll
    for (int m = 0; m < 4; m++)
#pragma unroll
        for (int nf = 0; nf < 4; nf++) acc[m][nf] = z;

    auto stage = [&](int t) {
#pragma unroll
        for (int p = 0; p < 4; ++p) {
            gload16(gA + p * rstep + t * 128, (char*)As + p * 4096 + wv * 1024);
            gload16(gB + p * rstep + t * 128, (char*)Bs + p * 4096 + wv * 1024);
        }
    };
    stage(0);

    for (int t = 0; t < LK / 128; ++t) {
        __syncthreads();
        i64 af[4][4], bv[4][4];
#pragma unroll
        for (int m = 0; m < 4; m++) {
            int row = qg * 64 + m * 16 + l15;
            const char* rp = (const char*)As + row * 128;
            int x = (row & 7) << 4;
#pragma unroll
            for (int kk = 0; kk < 4; kk++)
                af[m][kk] = *reinterpret_cast<const i64*>(rp + ((kk * 32 + g * 8) ^ x));
        }
#pragma unroll
        for (int nf = 0; nf < 4; nf++) {
            int row = dg * 64 + nf * 16 + l15;
            const char* rp = (const char*)Bs + row * 128;
            int x = (row & 7) << 4;
#pragma unroll
            for (int kk = 0; kk < 4; kk++)
                bv[nf][kk] = *reinterpret_cast<const i64*>(rp + ((kk * 32 + g * 8) ^ x));
        }
        __syncthreads();
        if (t + 1 < LK / 128) stage(t + 1);
#pragma unroll
        for (int kk = 0; kk < 4; kk++)
#pragma unroll
            for (int nf = 0; nf < 4; nf++)
#pragma unroll
                for (int m = 0; m < 4; m++)
                    acc[m][nf] = MFMAF8(af[m][kk], bv[nf][kk], acc[m][nf]);
    }
#pragma unroll
    for (int m = 0; m < 4; m++) {
        float rqv[4];
#pragma unroll
        for (int j = 0; j < 4; j++)
            rqv[j] = Rq[(size_t)b * LQ + q0 + qg * 64 + m * 16 + g * 4 + j];
#pragma unroll
        for (int nf = 0; nf < 4; nf++)
#pragma unroll
            for (int j = 0; j < 4; j++) {
                int q = q0 + qg * 64 + m * 16 + g * 4 + j;
                int d = n0 + dg * 64 + nf * 16 + l15;
                size_t idx = ((size_t)q * BB + b) * DD + d;
                tout[idx] = f2bf(query[idx] - acc[m][nf][j] * rqv[j]);
            }
    }
}

// out = relu( t @ Wtb^T ): 128x128 tile, bf16 staged, K=512
__global__ __launch_bounds__(256, 3) void k_final(const u16* __restrict__ t, const u16* __restrict__ Wtb,
                                                  float* __restrict__ out)
{
    const int r0 = blockIdx.x * 128, n0 = blockIdx.y * 128;
    const int tid = threadIdx.x, wv = tid >> 6, lane = tid & 63, l15 = lane & 15, g = lane >> 4;
    const int qg = wv >> 1, dg = wv & 1;

    __shared__ __align__(16) u16 As[128 * 64], Bs[128 * 64];

    const int srow = wv * 8 + (lane >> 3);
    const int scb = ((lane & 7) * 16) ^ ((srow & 7) << 4);
    const char* gA = (const char*)(t + (size_t)(r0 + srow) * DD) + scb;
    const char* gB = (const char*)(Wtb + (size_t)(n0 + srow) * DD) + scb;
    const size_t rstep = (size_t)32 * DD * 2;

    f32x4 z = {0.f, 0.f, 0.f, 0.f};
    f32x4 acc[4][4];
#pragma unroll
    for (int m = 0; m < 4; m++)
#pragma unroll
        for (int nf = 0; nf < 4; nf++) acc[m][nf] = z;

#pragma unroll
    for (int p = 0; p < 4; ++p) {
        gload16(gA + p * rstep, (char*)As + p * 4096 + wv * 1024);
        gload16(gB + p * rstep, (char*)Bs + p * 4096 + wv * 1024);
    }

    for (int tt = 0; tt < DD / 64; ++tt) {
        __syncthreads();
        bf16x8 af[4][2], bv[4][2];
#pragma unroll
        for (int m = 0; m < 4; m++) {
            int row = qg * 64 + m * 16 + l15;
            const char* rp = (const char*)As + row * 128;
            int x = (row & 7) << 4;
#pragma unroll
            for (int kk = 0; kk < 2; kk++)
                af[m][kk] = *reinterpret_cast<const bf16x8*>(rp + ((kk * 64 + g * 16) ^ x));
        }
#pragma unroll
        for (int nf = 0; nf < 4; nf++) {
            int row = dg * 64 + nf * 16 + l15;
            const char* rp = (const char*)Bs + row * 128;
            int x = (row & 7) << 4;
#pragma unroll
            for (int kk = 0; kk < 2; kk++)
                bv[nf][kk] = *reinterpret_cast<const bf16x8*>(rp + ((kk * 64 + g * 16) ^ x));
        }
        __syncthreads();
        if (tt + 1 < DD / 64) {
            int ktb = (tt + 1) * 128;
#pragma unroll
            for (int p = 0; p < 4; ++p) {
                gload16(gA + p * rstep + ktb, (char*)As + p * 4096 + wv * 1024);
                gload16(gB + p * rstep + ktb, (char*)Bs + p * 4096 + wv * 1024);
            }
        }
#pragma unroll
        for (int nf = 0; nf < 4; nf++)
#pragma unroll
            for (int m = 0; m < 4; m++) {
                acc[m][nf] = MFMA16(af[m][0], bv[nf][0], acc[m][nf]);
                acc[m][nf] = MFMA16(af[m][1], bv[nf][1], acc[m][nf]);
            }
    }
#pragma unroll
    for (int m = 0; m < 4; m++)
#pragma unroll
        for (int nf = 0; nf < 4; nf++)
#pragma unroll
            for (int j = 0; j < 4; j++)
                out[(size_t)(r0 + qg * 64 + m * 16 + g * 4 + j) * DD + n0 + dg * 64 + nf * 16 + l15] =
                    fmaxf(acc[m][nf][j], 0.f);
}

extern "C" void kernel_launch(void* const* d_in, const int* in_sizes, int n_in,
                              void* d_out, int out_size, void* d_ws, size_t ws_size,
                              hipStream_t stream)
{
    const float* query = (const float*)d_in[0];
    const float* key   = (const float*)d_in[1];
    const float* value = (const float*)d_in[2];
    const float* WK    = (const float*)d_in[3];
    const float* WQ    = (const float*)d_in[4];
    const float* WV    = (const float*)d_in[5];
    const float* Wt    = (const float*)d_in[6];
    float* out = (float*)d_out;

    char* ws = (char*)d_ws;
    u16*   wqb = (u16*)(ws);                                   //  4 MB [B][LQ][64] bf16
    u16*   wkb = (u16*)(ws + (4u << 20));                      //  4 MB [B][LK][64] bf16
    u8*    wvS = (u8*)(ws + (8u << 20));                       // 16 MB [B][512][LK] fp8
    u16*   t   = (u16*)(ws + (24u << 20));                     // 32 MB [LQ][B][512] bf16
    u16*   vb  = (u16*)(ws + (56u << 20));                     // 32 MB [B][LK][512] bf16
    float* Rq  = (float*)(ws + (88u << 20));                   // 128 KB [B][LQ] f32
    float* ci  = (float*)(ws + (88u << 20) + (128u << 10));    // 128 KB [B][LK] f32
    u16*   WQb = (u16*)(ws + (88u << 20) + (256u << 10));      // 64 KB
    u16*   WKb = (u16*)(ws + (88u << 20) + (320u << 10));      // 64 KB
    u16*   WVb = (u16*)(ws + (88u << 20) + (384u << 10));      // 512 KB
    u16*   Wtb = (u16*)(ws + (88u << 20) + (896u << 10));      // 512 KB

    // per-group buffers: E0 (4MB/b) + Rpart (1MB/b) + Cpart (128KB/b)
    const size_t fixed = 90ull << 20;
    const size_t perG = (4ull << 20) + (1ull << 20) + (128ull << 10);
    int G = 0;
    for (int g = 16; g >= 1; g >>= 1)
        if (fixed + (size_t)g * perG <= ws_size) { G = g; break; }
    if (G == 0) G = 1;
    u8*    E0    = (u8*)(ws + fixed);
    float* Rpart = (float*)(ws + fixed + ((size_t)G << 22));
    float* Cpart = (float*)(ws + fixed + ((size_t)G << 22) + ((size_t)G << 20));

    k_cvt<<<32, 256, 0, stream>>>(WQ, WQb, DKK * DD);
    k_cvt<<<32, 256, 0, stream>>>(WK, WKb, DKK * DD);
    k_cvt<<<256, 256, 0, stream>>>(WV, WVb, DD * DD);
    k_cvt<<<256, 256, 0, stream>>>(Wt, Wtb, DD * DD);
    k_cvtv<<<8192, 256, 0, stream>>>(value, vb);

    k_projqk<<<dim3(LQ / 64, BB, 2), 256, 0, stream>>>(query, key, WQb, WKb, wqb, wkb);

    for (int b0 = 0; b0 < BB; b0 += G) {
        k_score<<<dim3(LK / 64, LQ / 512, G), 256, 0, stream>>>(wqb, wkb, E0, Rpart, b0);
        k_rsum<<<G * 8, 256, 0, stream>>>(Rpart, Rq, b0);
        k_colsum<<<dim3(2, 16, G), 256, 0, stream>>>(E0, Rq, Cpart, b0);
        k_csum<<<G * 8, 256, 0, stream>>>(Cpart, ci, b0);
        k_projv<<<dim3(LK / 128, DD / 128, G), 256, 0, stream>>>(vb, WVb, ci, wvS, b0);
        k_pvgemm<<<64 * G, 256, 0, stream>>>(query, E0, wvS, Rq, t, b0, G);
    }

    k_final<<<dim3(LQ * BB / 128, DD / 128), 256, 0, stream>>>(t, Wtb, out);
}

// Round 10
// 297.581 us; speedup vs baseline: 2.2206x; 1.0202x over previous
//
#include <hip/hip_runtime.h>

#define LQ 2048
#define LK 2048
#define BB 16
#define DD 512
#define DKK 64
#define EPSF 1e-9f

typedef unsigned short u16;
typedef unsigned char u8;
typedef long i64;
typedef __attribute__((ext_vector_type(8))) short bf16x8;
typedef __attribute__((ext_vector_type(4))) float f32x4;
#define MFMA16(a, b, c) __builtin_amdgcn_mfma_f32_16x16x32_bf16(a, b, c, 0, 0, 0)
#define MFMAF8(a, b, c) __builtin_amdgcn_mfma_f32_16x16x32_fp8_fp8(a, b, c, 0, 0, 0)

__device__ inline u16 f2bf(float f) {
    unsigned int u = __float_as_uint(f);
    u += 0x7fffu + ((u >> 16) & 1u);   // RNE
    return (u16)(u >> 16);
}
__device__ inline bf16x8 cvt8(float4 a, float4 b) {
    bf16x8 r;
    r[0] = (short)f2bf(a.x); r[1] = (short)f2bf(a.y); r[2] = (short)f2bf(a.z); r[3] = (short)f2bf(a.w);
    r[4] = (short)f2bf(b.x); r[5] = (short)f2bf(b.y); r[6] = (short)f2bf(b.z); r[7] = (short)f2bf(b.w);
    return r;
}
__device__ inline int pk_fp8x4(float a, float b, float c, float d) {
    int r = __builtin_amdgcn_cvt_pk_fp8_f32(a, b, 0, false);
    r = __builtin_amdgcn_cvt_pk_fp8_f32(c, d, r, true);
    return r;
}
__device__ inline void gload16(const void* g, void* l) {
    __builtin_amdgcn_global_load_lds((const __attribute__((address_space(1))) unsigned int*)g,
                                     (__attribute__((address_space(3))) unsigned int*)l, 16, 0, 0);
}

__global__ __launch_bounds__(256) void k_cvt(const float* __restrict__ src, u16* __restrict__ dst, int n) {
    int i = (blockIdx.x * 256 + threadIdx.x) * 4;
    if (i < n) {
        float4 v = *reinterpret_cast<const float4*>(src + i);
        *reinterpret_cast<ushort4*>(dst + i) = make_ushort4(f2bf(v.x), f2bf(v.y), f2bf(v.z), f2bf(v.w));
    }
}

// value f32 [LK][B][D] -> vb bf16 [B][LK][D]
__global__ __launch_bounds__(256) void k_cvtv(const float* __restrict__ value, u16* __restrict__ vb) {
    size_t i = ((size_t)blockIdx.x * 256 + threadIdx.x) * 8;
    int k = (int)(i >> 13);
    int r = (int)(i & 8191);
    int b = r >> 9, d = r & 511;
    float4 a = *reinterpret_cast<const float4*>(value + i);
    float4 c = *reinterpret_cast<const float4*>(value + i + 4);
    *reinterpret_cast<bf16x8*>(vb + ((size_t)b * LK + k) * DD + d) = cvt8(a, c);
}

// fused q/k projection + l2norm
__global__ __launch_bounds__(256) void k_projqk(const float* __restrict__ xq, const float* __restrict__ xk,
                                                const u16* __restrict__ Wq, const u16* __restrict__ Wk,
                                                u16* __restrict__ yq, u16* __restrict__ yk)
{
    const float* x = blockIdx.z ? xk : xq;
    const u16* Wb = blockIdx.z ? Wk : Wq;
    u16* y = blockIdx.z ? yk : yq;
    const int b = blockIdx.y, r0 = blockIdx.x * 64;
    const int tid = threadIdx.x, wave = tid >> 6, lane = tid & 63, l15 = lane & 15, g = lane >> 4;
    const int rw = r0 + wave * 16;
    f32x4 z = {0.f, 0.f, 0.f, 0.f};
    f32x4 acc[4];
#pragma unroll
    for (int nf = 0; nf < 4; nf++) acc[nf] = z;

    for (int kt = 0; kt < DD; kt += 32) {
        const float* p = x + ((size_t)(rw + l15) * BB + b) * DD + kt + g * 8;
        bf16x8 af = cvt8(*reinterpret_cast<const float4*>(p), *reinterpret_cast<const float4*>(p + 4));
#pragma unroll
        for (int nf = 0; nf < 4; nf++) {
            bf16x8 bf_ = *reinterpret_cast<const bf16x8*>(Wb + (size_t)(nf * 16 + l15) * DD + kt + g * 8);
            acc[nf] = MFMA16(af, bf_, acc[nf]);
        }
    }
    float rn[4];
#pragma unroll
    for (int j = 0; j < 4; j++) {
        float t2 = acc[0][j] * acc[0][j] + acc[1][j] * acc[1][j]
                 + acc[2][j] * acc[2][j] + acc[3][j] * acc[3][j];
        t2 += __shfl_xor(t2, 1, 64);
        t2 += __shfl_xor(t2, 2, 64);
        t2 += __shfl_xor(t2, 4, 64);
        t2 += __shfl_xor(t2, 8, 64);
        rn[j] = 1.f / fmaxf(sqrtf(t2), 1e-12f);
    }
#pragma unroll
    for (int nf = 0; nf < 4; nf++)
#pragma unroll
        for (int j = 0; j < 4; j++) {
            int q = rw + g * 4 + j;
            y[((size_t)b * LQ + q) * DKK + nf * 16 + l15] = f2bf(acc[nf][j] * rn[j]);
        }
}

// Single QK^T pass, LDS-staged coalesced E0 writes.
// E0[bl][q][k] = fp8(exp(s_qk)); Rpart[bl][kb*4+w][q] = partial row sums.
// grid (LK/64, LQ/512, G). LDS tile 128q x 64k, row stride 80B (bank-conflict-free writes).
__global__ __launch_bounds__(256) void k_score(const u16* __restrict__ wqb, const u16* __restrict__ wkb,
                                               u8* __restrict__ E0, float* __restrict__ Rpart, int b0)
{
    const int kb = blockIdx.x, c512 = blockIdx.y * 512, bl = blockIdx.z, b = b0 + bl;
    const int tid = threadIdx.x, w = tid >> 6, lane = tid & 63, l15 = lane & 15, g = lane >> 4;
    const int k0 = kb * 64;
    f32x4 z = {0.f, 0.f, 0.f, 0.f};
    __shared__ __align__(16) u8 Elds[128 * 80];

    const u16* ar = wkb + ((size_t)b * LK + k0 + w * 16 + l15) * DKK;
    bf16x8 af0 = *reinterpret_cast<const bf16x8*>(ar + g * 8);
    bf16x8 af1 = *reinterpret_cast<const bf16x8*>(ar + 32 + g * 8);
    u8* Eb = E0 + (size_t)bl * LQ * LK;
    float* Rp = Rpart + ((size_t)bl * 128 + kb * 4 + w) * LQ;

    for (int ct = 0; ct < 4; ct++) {
#pragma unroll
        for (int qf = 0; qf < 8; qf++) {
            int q = c512 + ct * 128 + qf * 16 + l15;
            const u16* br = wqb + ((size_t)b * LQ + q) * DKK;
            bf16x8 b0v = *reinterpret_cast<const bf16x8*>(br + g * 8);
            bf16x8 b1v = *reinterpret_cast<const bf16x8*>(br + 32 + g * 8);
            f32x4 s = z;
            s = MFMA16(af0, b0v, s);
            s = MFMA16(af1, b1v, s);
            float pe[4];
#pragma unroll
            for (int j = 0; j < 4; j++) pe[j] = __expf(s[j]);
            *reinterpret_cast<int*>(Elds + (qf * 16 + l15) * 80 + w * 16 + g * 4) =
                pk_fp8x4(pe[0], pe[1], pe[2], pe[3]);
            float v = pe[0] + pe[1] + pe[2] + pe[3];
            v += __shfl_xor(v, 16, 64);
            v += __shfl_xor(v, 32, 64);
            if (g == 0) Rp[q] = v;
        }
        __syncthreads();
        // write out 128 rows x 64B: 4 lanes per row -> complete 64B sectors
#pragma unroll
        for (int it = 0; it < 2; it++) {
            int t = it * 256 + tid;
            int r = t >> 2, cc = t & 3;
            uint4 v = *reinterpret_cast<const uint4*>(Elds + r * 80 + cc * 16);
            *reinterpret_cast<uint4*>(Eb + (size_t)(c512 + ct * 128 + r) * LK + k0 + cc * 16) = v;
        }
        __syncthreads();
    }
}

// Rq[b][q] = 1 / sum_p Rpart[bl][p][q]
__global__ __launch_bounds__(256) void k_rsum(const float* __restrict__ Rpart, float* __restrict__ Rq, int b0) {
    int idx = blockIdx.x * 256 + threadIdx.x;
    int bl = idx >> 11, q = idx & 2047;
    const float* rp = Rpart + (size_t)bl * 128 * LQ + q;
    float s = 0.f;
    for (int p = 0; p < 128; p++) s += rp[(size_t)p * LQ];
    Rq[(size_t)(b0 + bl) * LQ + q] = 1.f / s;
}

// Cpart[bl][qc][k] = sum over 128 q of E0[q][k]*Rq[q].  grid (2, 16, G)
__global__ __launch_bounds__(256) void k_colsum(const u8* __restrict__ E0, const float* __restrict__ Rq,
                                                float* __restrict__ Cpart, int b0)
{
    const int kc = blockIdx.x, qc = blockIdx.y, bl = blockIdx.z;
    const int tid = threadIdx.x, sub = tid >> 6, lane = tid & 63;
    const u8* Eb = E0 + (size_t)bl * LQ * LK + (size_t)kc * 1024 + lane * 16;
    const float* rq = Rq + (size_t)(b0 + bl) * LQ + qc * 128;
    float acc[16];
#pragma unroll
    for (int i = 0; i < 16; i++) acc[i] = 0.f;
    for (int qi = 0; qi < 32; qi++) {
        int q = qi * 4 + sub;
        uint4 raw = *reinterpret_cast<const uint4*>(Eb + (size_t)(qc * 128 + q) * LK);
        float w = rq[q];
        const unsigned int* rw = (const unsigned int*)&raw;
#pragma unroll
        for (int dw = 0; dw < 4; dw++) {
            unsigned int u = rw[dw];
#pragma unroll
            for (int by = 0; by < 4; by++) {
                // e4m3fn -> f32 for positive normals (E0 in [0.37, 2.72])
                unsigned int f = 0x3C000000u + (((u >> (8 * by)) & 0x7Fu) << 20);
                acc[dw * 4 + by] += __uint_as_float(f) * w;
            }
        }
    }
    __shared__ float red[4][64][16];
#pragma unroll
    for (int i = 0; i < 16; i++) red[sub][lane][i] = acc[i];
    __syncthreads();
    if (sub == 0) {
#pragma unroll
        for (int i = 0; i < 16; i++) {
            float v = red[0][lane][i] + red[1][lane][i] + red[2][lane][i] + red[3][lane][i];
            Cpart[((size_t)bl * 16 + qc) * LK + kc * 1024 + lane * 16 + i] = v;
        }
    }
}

// ci[b][k] = 1/(eps + sum_qc Cpart)
__global__ __launch_bounds__(256) void k_csum(const float* __restrict__ Cpart, float* __restrict__ ci, int b0) {
    int idx = blockIdx.x * 256 + threadIdx.x;
    int bl = idx >> 11, k = idx & 2047;
    const float* cp = Cpart + (size_t)bl * 16 * LK + k;
    float s = 0.f;
#pragma unroll
    for (int p = 0; p < 16; p++) s += cp[(size_t)p * LK];
    ci[(size_t)(b0 + bl) * LK + k] = 1.f / (EPSF + s);
}

// wvS[b][d][k] = fp8( (vb[b][k,:] @ WVb[d,:]) * ci[b][k] )  -- staged GEMM
__global__ __launch_bounds__(256, 3) void k_projv(const u16* __restrict__ vb, const u16* __restrict__ WVb,
                                                  const float* __restrict__ ci, u8* __restrict__ wvS, int b0)
{
    const int b = b0 + blockIdx.z, k0 = blockIdx.x * 128, n0 = blockIdx.y * 128;
    const int tid = threadIdx.x, wv = tid >> 6, lane = tid & 63, l15 = lane & 15, g = lane >> 4;
    const int qg = wv >> 1, dg = wv & 1;

    __shared__ __align__(16) u16 As[128 * 64], Bs[128 * 64];

    const int srow = wv * 8 + (lane >> 3);
    const int scb = ((lane & 7) * 16) ^ ((srow & 7) << 4);
    const char* gA = (const char*)(vb + ((size_t)b * LK + k0 + srow) * DD) + scb;
    const char* gB = (const char*)(WVb + (size_t)(n0 + srow) * DD) + scb;
    const size_t rstep = (size_t)32 * DD * 2;

    f32x4 z = {0.f, 0.f, 0.f, 0.f};
    f32x4 acc[4][4];
#pragma unroll
    for (int m = 0; m < 4; m++)
#pragma unroll
        for (int nf = 0; nf < 4; nf++) acc[m][nf] = z;

#pragma unroll
    for (int p = 0; p < 4; ++p) {
        gload16(gA + p * rstep, (char*)As + p * 4096 + wv * 1024);
        gload16(gB + p * rstep, (char*)Bs + p * 4096 + wv * 1024);
    }

    for (int tt = 0; tt < DD / 64; ++tt) {
        __syncthreads();
        bf16x8 af[4][2], bv[4][2];
#pragma unroll
        for (int m = 0; m < 4; m++) {
            int row = qg * 64 + m * 16 + l15;
            const char* rp = (const char*)As + row * 128;
            int x = (row & 7) << 4;
#pragma unroll
            for (int kk = 0; kk < 2; kk++)
                af[m][kk] = *reinterpret_cast<const bf16x8*>(rp + ((kk * 64 + g * 16) ^ x));
        }
#pragma unroll
        for (int nf = 0; nf < 4; nf++) {
            int row = dg * 64 + nf * 16 + l15;
            const char* rp = (const char*)Bs + row * 128;
            int x = (row & 7) << 4;
#pragma unroll
            for (int kk = 0; kk < 2; kk++)
                bv[nf][kk] = *reinterpret_cast<const bf16x8*>(rp + ((kk * 64 + g * 16) ^ x));
        }
        __syncthreads();
        if (tt + 1 < DD / 64) {
            int ktb = (tt + 1) * 128;
#pragma unroll
            for (int p = 0; p < 4; ++p) {
                gload16(gA + p * rstep + ktb, (char*)As + p * 4096 + wv * 1024);
                gload16(gB + p * rstep + ktb, (char*)Bs + p * 4096 + wv * 1024);
            }
        }
#pragma unroll
        for (int nf = 0; nf < 4; nf++)
#pragma unroll
            for (int m = 0; m < 4; m++) {
                acc[m][nf] = MFMA16(af[m][0], bv[nf][0], acc[m][nf]);
                acc[m][nf] = MFMA16(af[m][1], bv[nf][1], acc[m][nf]);
            }
    }
#pragma unroll
    for (int m = 0; m < 4; m++) {
        float cv[4];
        int kb = k0 + qg * 64 + m * 16 + g * 4;
#pragma unroll
        for (int j = 0; j < 4; j++) cv[j] = ci[(size_t)b * LK + kb + j];
#pragma unroll
        for (int nf = 0; nf < 4; nf++) {
            int d = n0 + dg * 64 + nf * 16 + l15;
            *reinterpret_cast<int*>(wvS + ((size_t)b * DD + d) * LK + kb) =
                pk_fp8x4(acc[m][nf][0] * cv[0], acc[m][nf][1] * cv[1],
                         acc[m][nf][2] * cv[2], acc[m][nf][3] * cv[3]);
        }
    }
}

// t[q,b,:] = query - Rq[q] * (E0 @ wvS^T).  fp8 GEMM, BK=128, LDS-staged
__global__ __launch_bounds__(256, 3) void k_pvgemm(const float* __restrict__ query,
                                                   const u8* __restrict__ E0,
                                                   const u8* __restrict__ wvS,
                                                   const float* __restrict__ Rq,
                                                   u16* __restrict__ tout, int b0, int G)
{
    const int i = blockIdx.x;
    int bl, tile;
    if (G == 16) { bl = (i & 7) + 8 * (i >> 9); tile = (i >> 3) & 63; }
    else         { bl = i % G; tile = i / G; }
    const int b = b0 + bl;
    const int q0 = (tile >> 2) * 128, n0 = (tile & 3) * 128;
    const int tid = threadIdx.x, wv = tid >> 6, lane = tid & 63, l15 = lane & 15, g = lane >> 4;
    const int qg = wv >> 1, dg = wv & 1;

    __shared__ __align__(16) char As[16384], Bs[16384];

    const u8* Eb = E0 + (size_t)bl * LQ * LK;
    const u8* Vb = wvS + (size_t)b * DD * LK;

    const int srow = wv * 8 + (lane >> 3);
    const int scb = ((lane & 7) * 16) ^ ((srow & 7) << 4);
    const char* gA = (const char*)Eb + (size_t)(q0 + srow) * LK + scb;
    const char* gB = (const char*)Vb + (size_t)(n0 + srow) * LK + scb;
    const size_t rstep = (size_t)32 * LK;

    f32x4 z = {0.f, 0.f, 0.f, 0.f};
    f32x4 acc[4][4];
#pragma unroll
    for (int m = 0; m < 4; m++)
#pragma unroll
        for (int nf = 0; nf < 4; nf++) acc[m][nf] = z;

    auto stage = [&](int t) {
#pragma unroll
        for (int p = 0; p < 4; ++p) {
            gload16(gA + p * rstep + t * 128, (char*)As + p * 4096 + wv * 1024);
            gload16(gB + p * rstep + t * 128, (char*)Bs + p * 4096 + wv * 1024);
        }
    };
    stage(0);

    for (int t = 0; t < LK / 128; ++t) {
        __syncthreads();
        i64 af[4][4], bv[4][4];
#pragma unroll
        for (int m = 0; m < 4; m++) {
            int row = qg * 64 + m * 16 + l15;
            const char* rp = (const char*)As + row * 128;
            int x = (row & 7) << 4;
#pragma unroll
            for (int kk = 0; kk < 4; kk++)
                af[m][kk] = *reinterpret_cast<const i64*>(rp + ((kk * 32 + g * 8) ^ x));
        }
#pragma unroll
        for (int nf = 0; nf < 4; nf++) {
            int row = dg * 64 + nf * 16 + l15;
            const char* rp = (const char*)Bs + row * 128;
            int x = (row & 7) << 4;
#pragma unroll
            for (int kk = 0; kk < 4; kk++)
                bv[nf][kk] = *reinterpret_cast<const i64*>(rp + ((kk * 32 + g * 8) ^ x));
        }
        __syncthreads();
        if (t + 1 < LK / 128) stage(t + 1);
#pragma unroll
        for (int kk = 0; kk < 4; kk++)
#pragma unroll
            for (int nf = 0; nf < 4; nf++)
#pragma unroll
                for (int m = 0; m < 4; m++)
                    acc[m][nf] = MFMAF8(af[m][kk], bv[nf][kk], acc[m][nf]);
    }
#pragma unroll
    for (int m = 0; m < 4; m++) {
        float rqv[4];
#pragma unroll
        for (int j = 0; j < 4; j++)
            rqv[j] = Rq[(size_t)b * LQ + q0 + qg * 64 + m * 16 + g * 4 + j];
#pragma unroll
        for (int nf = 0; nf < 4; nf++)
#pragma unroll
            for (int j = 0; j < 4; j++) {
                int q = q0 + qg * 64 + m * 16 + g * 4 + j;
                int d = n0 + dg * 64 + nf * 16 + l15;
                size_t idx = ((size_t)q * BB + b) * DD + d;
                tout[idx] = f2bf(query[idx] - acc[m][nf][j] * rqv[j]);
            }
    }
}

// out = relu( t @ Wtb^T ): 128x128 tile, bf16 staged, K=512
__global__ __launch_bounds__(256, 3) void k_final(const u16* __restrict__ t, const u16* __restrict__ Wtb,
                                                  float* __restrict__ out)
{
    const int r0 = blockIdx.x * 128, n0 = blockIdx.y * 128;
    const int tid = threadIdx.x, wv = tid >> 6, lane = tid & 63, l15 = lane & 15, g = lane >> 4;
    const int qg = wv >> 1, dg = wv & 1;

    __shared__ __align__(16) u16 As[128 * 64], Bs[128 * 64];

    const int srow = wv * 8 + (lane >> 3);
    const int scb = ((lane & 7) * 16) ^ ((srow & 7) << 4);
    const char* gA = (const char*)(t + (size_t)(r0 + srow) * DD) + scb;
    const char* gB = (const char*)(Wtb + (size_t)(n0 + srow) * DD) + scb;
    const size_t rstep = (size_t)32 * DD * 2;

    f32x4 z = {0.f, 0.f, 0.f, 0.f};
    f32x4 acc[4][4];
#pragma unroll
    for (int m = 0; m < 4; m++)
#pragma unroll
        for (int nf = 0; nf < 4; nf++) acc[m][nf] = z;

#pragma unroll
    for (int p = 0; p < 4; ++p) {
        gload16(gA + p * rstep, (char*)As + p * 4096 + wv * 1024);
        gload16(gB + p * rstep, (char*)Bs + p * 4096 + wv * 1024);
    }

    for (int tt = 0; tt < DD / 64; ++tt) {
        __syncthreads();
        bf16x8 af[4][2], bv[4][2];
#pragma unroll
        for (int m = 0; m < 4; m++) {
            int row = qg * 64 + m * 16 + l15;
            const char* rp = (const char*)As + row * 128;
            int x = (row & 7) << 4;
#pragma unroll
            for (int kk = 0; kk < 2; kk++)
                af[m][kk] = *reinterpret_cast<const bf16x8*>(rp + ((kk * 64 + g * 16) ^ x));
        }
#pragma unroll
        for (int nf = 0; nf < 4; nf++) {
            int row = dg * 64 + nf * 16 + l15;
            const char* rp = (const char*)Bs + row * 128;
            int x = (row & 7) << 4;
#pragma unroll
            for (int kk = 0; kk < 2; kk++)
                bv[nf][kk] = *reinterpret_cast<const bf16x8*>(rp + ((kk * 64 + g * 16) ^ x));
        }
        __syncthreads();
        if (tt + 1 < DD / 64) {
            int ktb = (tt + 1) * 128;
#pragma unroll
            for (int p = 0; p < 4; ++p) {
                gload16(gA + p * rstep + ktb, (char*)As + p * 4096 + wv * 1024);
                gload16(gB + p * rstep + ktb, (char*)Bs + p * 4096 + wv * 1024);
            }
        }
#pragma unroll
        for (int nf = 0; nf < 4; nf++)
#pragma unroll
            for (int m = 0; m < 4; m++) {
                acc[m][nf] = MFMA16(af[m][0], bv[nf][0], acc[m][nf]);
                acc[m][nf] = MFMA16(af[m][1], bv[nf][1], acc[m][nf]);
            }
    }
#pragma unroll
    for (int m = 0; m < 4; m++)
#pragma unroll
        for (int nf = 0; nf < 4; nf++)
#pragma unroll
            for (int j = 0; j < 4; j++)
                out[(size_t)(r0 + qg * 64 + m * 16 + g * 4 + j) * DD + n0 + dg * 64 + nf * 16 + l15] =
                    fmaxf(acc[m][nf][j], 0.f);
}

extern "C" void kernel_launch(void* const* d_in, const int* in_sizes, int n_in,
                              void* d_out, int out_size, void* d_ws, size_t ws_size,
                              hipStream_t stream)
{
    const float* query = (const float*)d_in[0];
    const float* key   = (const float*)d_in[1];
    const float* value = (const float*)d_in[2];
    const float* WK    = (const float*)d_in[3];
    const float* WQ    = (const float*)d_in[4];
    const float* WV    = (const float*)d_in[5];
    const float* Wt    = (const float*)d_in[6];
    float* out = (float*)d_out;

    char* ws = (char*)d_ws;
    u16*   wqb = (u16*)(ws);                                   //  4 MB [B][LQ][64] bf16
    u16*   wkb = (u16*)(ws + (4u << 20));                      //  4 MB [B][LK][64] bf16
    u8*    wvS = (u8*)(ws + (8u << 20));                       // 16 MB [B][512][LK] fp8
    u16*   t   = (u16*)(ws + (24u << 20));                     // 32 MB [LQ][B][512] bf16
    u16*   vb  = (u16*)(ws + (56u << 20));                     // 32 MB [B][LK][512] bf16
    float* Rq  = (float*)(ws + (88u << 20));                   // 128 KB [B][LQ] f32
    float* ci  = (float*)(ws + (88u << 20) + (128u << 10));    // 128 KB [B][LK] f32
    u16*   WQb = (u16*)(ws + (88u << 20) + (256u << 10));      // 64 KB
    u16*   WKb = (u16*)(ws + (88u << 20) + (320u << 10));      // 64 KB
    u16*   WVb = (u16*)(ws + (88u << 20) + (384u << 10));      // 512 KB
    u16*   Wtb = (u16*)(ws + (88u << 20) + (896u << 10));      // 512 KB

    // per-group buffers: E0 (4MB/b) + Rpart (1MB/b) + Cpart (128KB/b)
    const size_t fixed = 90ull << 20;
    const size_t perG = (4ull << 20) + (1ull << 20) + (128ull << 10);
    int G = 0;
    for (int g = 16; g >= 1; g >>= 1)
        if (fixed + (size_t)g * perG <= ws_size) { G = g; break; }
    if (G == 0) G = 1;
    u8*    E0    = (u8*)(ws + fixed);
    float* Rpart = (float*)(ws + fixed + ((size_t)G << 22));
    float* Cpart = (float*)(ws + fixed + ((size_t)G << 22) + ((size_t)G << 20));

    k_cvt<<<32, 256, 0, stream>>>(WQ, WQb, DKK * DD);
    k_cvt<<<32, 256, 0, stream>>>(WK, WKb, DKK * DD);
    k_cvt<<<256, 256, 0, stream>>>(WV, WVb, DD * DD);
    k_cvt<<<256, 256, 0, stream>>>(Wt, Wtb, DD * DD);
    k_cvtv<<<8192, 256, 0, stream>>>(value, vb);

    k_projqk<<<dim3(LQ / 64, BB, 2), 256, 0, stream>>>(query, key, WQb, WKb, wqb, wkb);

    for (int b0 = 0; b0 < BB; b0 += G) {
        k_score<<<dim3(LK / 64, LQ / 512, G), 256, 0, stream>>>(wqb, wkb, E0, Rpart, b0);
        k_rsum<<<G * 8, 256, 0, stream>>>(Rpart, Rq, b0);
        k_colsum<<<dim3(2, 16, G), 256, 0, stream>>>(E0, Rq, Cpart, b0);
        k_csum<<<G * 8, 256, 0, stream>>>(Cpart, ci, b0);
        k_projv<<<dim3(LK / 128, DD / 128, G), 256, 0, stream>>>(vb, WVb, ci, wvS, b0);
        k_pvgemm<<<64 * G, 256, 0, stream>>>(query, E0, wvS, Rq, t, b0, G);
    }

    k_final<<<dim3(LQ * BB / 128, DD / 128), 256, 0, stream>>>(t, Wtb, out);
}